// Round 1
// baseline (1496.741 us; speedup 1.0000x reference)
//
#include <hip/hip_runtime.h>
#include <math.h>

typedef unsigned int u32;
typedef unsigned long long u64;

#define KANC 18376
#define PRE 2000
#define PREP 2048
#define POST 300

#define OUT_CLS 0
#define OUT_REG 73504
#define OUT_ROI 220512
#define OUT_RID 222912
#define OUT_ANC 223512

// ws byte offsets
#define WS_SHARED 0u
#define WS_VPOS   16777216u
#define WS_BOXES  16924672u
#define WS_KEYS   17512704u
#define WS_TOPBOX 17659712u
#define WS_TOPKEY 17725248u
#define WS_MASK   17741632u

__device__ __forceinline__ void anchor_base(int t, float& y1, float& x1, float& y2, float& x2) {
    // matches numpy _anchor_base: double math narrowed to f32
    const double ratios[3] = {0.5, 1.0, 2.0};
    const double scales[3] = {8.0, 16.0, 32.0};
    double r = ratios[t / 3], s = scales[t % 3];
    double h = 16.0 * s * sqrt(r);
    double w = 16.0 * s * sqrt(1.0 / r);
    y1 = (float)(8.0 - h * 0.5);
    x1 = (float)(8.0 - w * 0.5);
    y2 = (float)(8.0 + h * 0.5);
    x2 = (float)(8.0 + w * 0.5);
}

// ---------------- K0: anchors + valid-position map ----------------
__global__ __launch_bounds__(1024) void k0_anchors(float* out, int* vpos,
                                                   const int* d_imgh, const int* d_imgw) {
    int tid = threadIdx.x;
    float imgh = (float)d_imgh[0], imgw = (float)d_imgw[0];
    __shared__ int cnt[1024];
    int base = tid * 36;
    int c = 0;
    for (int k = 0; k < 36; k++) {
        int a = base + k;
        int t = a % 9; int pix = a / 9; int x = pix & 63; int y = pix >> 6;
        float b0, b1, b2, b3; anchor_base(t, b0, b1, b2, b3);
        float a0 = b0 + 16.0f * y, a1 = b1 + 16.0f * x;
        float a2 = b2 + 16.0f * y, a3 = b3 + 16.0f * x;
        out[OUT_ANC + a * 4 + 0] = a0;
        out[OUT_ANC + a * 4 + 1] = a1;
        out[OUT_ANC + a * 4 + 2] = a2;
        out[OUT_ANC + a * 4 + 3] = a3;
        if (a0 >= 0.0f && a1 >= 0.0f && a2 <= imgh && a3 <= imgw) c++;
    }
    cnt[tid] = c;
    __syncthreads();
    for (int off = 1; off < 1024; off <<= 1) {
        int v = cnt[tid];
        int u = (tid >= off) ? cnt[tid - off] : 0;
        __syncthreads();
        cnt[tid] = v + u;
        __syncthreads();
    }
    int j = (tid == 0) ? 0 : cnt[tid - 1];
    for (int k = 0; k < 36; k++) {
        int a = base + k;
        int t = a % 9; int pix = a / 9; int x = pix & 63; int y = pix >> 6;
        float b0, b1, b2, b3; anchor_base(t, b0, b1, b2, b3);
        float a0 = b0 + 16.0f * y, a1 = b1 + 16.0f * x;
        float a2 = b2 + 16.0f * y, a3 = b3 + 16.0f * x;
        bool ok = (a0 >= 0.0f && a1 >= 0.0f && a2 <= imgh && a3 <= imgw);
        vpos[a] = ok ? j : -1;
        if (ok) j++;
    }
}

// ---------------- K1: 3x3 conv 512->512 + bias + relu (fp32) ----------------
#define TCI 16
__global__ __launch_bounds__(256) void k1_conv(const float* __restrict__ feat,
                                               const float* __restrict__ wgt,
                                               const float* __restrict__ bias,
                                               float* __restrict__ sh_out) {
    int row = blockIdx.x;               // b*64 + y
    int b = row >> 6, y = row & 63;
    int cob = blockIdx.y * 64;
    __shared__ float Al[TCI * 3 * 66];  // [ci][dy][xi], xi = x+1
    __shared__ float Wl[TCI * 9 * 64];  // [k][co]
    int tid = threadIdx.x;
    float acc[16];
#pragma unroll
    for (int i = 0; i < 16; i++) acc[i] = 0.0f;
    int px0 = (tid & 15) * 4;
    int co0 = (tid >> 4) * 4;
    for (int cib = 0; cib < 512; cib += TCI) {
        for (int s = tid; s < TCI * 198; s += 256) {
            int c = s / 198; int rem = s - c * 198;
            int dy = rem / 66; int xi = rem - dy * 66;
            int yy = y + dy - 1; int xx = xi - 1;
            float v = 0.0f;
            if (yy >= 0 && yy < 64 && xx >= 0 && xx < 64)
                v = feat[((b * 512 + cib + c) * 64 + yy) * 64 + xx];
            Al[s] = v;
        }
        for (int s = tid; s < 64 * 36; s += 256) {
            int co = s / 36; int q = s - co * 36;
            const float4 w4 = *(const float4*)(wgt + (size_t)(cob + co) * 4608 + cib * 9 + q * 4);
            int k = q * 4;
            Wl[(k + 0) * 64 + co] = w4.x;
            Wl[(k + 1) * 64 + co] = w4.y;
            Wl[(k + 2) * 64 + co] = w4.z;
            Wl[(k + 3) * 64 + co] = w4.w;
        }
        __syncthreads();
#pragma unroll 2
        for (int c = 0; c < TCI; c++) {
#pragma unroll
            for (int ky = 0; ky < 3; ky++) {
                const float* arow = &Al[(c * 3 + ky) * 66];
#pragma unroll
                for (int kx = 0; kx < 3; kx++) {
                    int k = c * 9 + ky * 3 + kx;
                    float4 w4 = *(const float4*)&Wl[k * 64 + co0];
                    float a0 = arow[px0 + kx + 0];
                    float a1 = arow[px0 + kx + 1];
                    float a2 = arow[px0 + kx + 2];
                    float a3 = arow[px0 + kx + 3];
                    acc[0]  += a0 * w4.x; acc[1]  += a0 * w4.y; acc[2]  += a0 * w4.z; acc[3]  += a0 * w4.w;
                    acc[4]  += a1 * w4.x; acc[5]  += a1 * w4.y; acc[6]  += a1 * w4.z; acc[7]  += a1 * w4.w;
                    acc[8]  += a2 * w4.x; acc[9]  += a2 * w4.y; acc[10] += a2 * w4.z; acc[11] += a2 * w4.w;
                    acc[12] += a3 * w4.x; acc[13] += a3 * w4.y; acc[14] += a3 * w4.z; acc[15] += a3 * w4.w;
                }
            }
        }
        __syncthreads();
    }
#pragma unroll
    for (int cc = 0; cc < 4; cc++) {
        float vb = bias[cob + co0 + cc];
        float4 o;
        o.x = fmaxf(acc[0 + cc]  + vb, 0.0f);
        o.y = fmaxf(acc[4 + cc]  + vb, 0.0f);
        o.z = fmaxf(acc[8 + cc]  + vb, 0.0f);
        o.w = fmaxf(acc[12 + cc] + vb, 0.0f);
        *(float4*)&sh_out[((size_t)(b * 512 + cob + co0 + cc) * 64 + y) * 64 + px0] = o;
    }
}

// ---------------- K2: 1x1 heads + softmax + decode + score keys ----------------
__global__ __launch_bounds__(256) void k2_heads(const float* __restrict__ sh_in,
                                                const float* __restrict__ cls_w,
                                                const float* __restrict__ cls_b,
                                                const float* __restrict__ reg_w,
                                                const float* __restrict__ reg_b,
                                                const int* __restrict__ vpos,
                                                float* __restrict__ out,
                                                float* __restrict__ boxes_ws,
                                                u32* __restrict__ keys_ws,
                                                const int* d_imgh, const int* d_imgw) {
    int row = blockIdx.x;           // b*64 + y
    int b = row >> 6, y = row & 63;
    int tid = threadIdx.x;
    __shared__ float Al[64 * 64];   // [ci][p]
    __shared__ float Wl[54 * 64];   // [o][ci]
    __shared__ float Ob[54 * 64];   // [o][p]
    int p = tid & 63, g = tid >> 6;
    int o0 = g * 14;
    int no = (g == 3) ? 12 : 14;
    float acc[14];
#pragma unroll
    for (int i = 0; i < 14; i++) acc[i] = 0.0f;
    for (int cib = 0; cib < 512; cib += 64) {
        for (int s = tid; s < 4096; s += 256) {
            int kk = s >> 6, pp = s & 63;
            Al[s] = sh_in[((size_t)(b * 512 + cib + kk) * 64 + y) * 64 + pp];
        }
        for (int s = tid; s < 54 * 64; s += 256) {
            int o = s >> 6, kk = s & 63;
            Wl[s] = (o < 18) ? cls_w[o * 512 + cib + kk] : reg_w[(o - 18) * 512 + cib + kk];
        }
        __syncthreads();
        for (int kk = 0; kk < 64; kk++) {
            float a = Al[kk * 64 + p];
#pragma unroll
            for (int oo = 0; oo < 14; oo++)
                if (oo < no) acc[oo] += a * Wl[(o0 + oo) * 64 + kk];
        }
        __syncthreads();
    }
#pragma unroll
    for (int oo = 0; oo < 14; oo++)
        if (oo < no) {
            int o = o0 + oo;
            float bv = (o < 18) ? cls_b[o] : reg_b[o - 18];
            Ob[o * 64 + p] = acc[oo] + bv;
        }
    __syncthreads();
    float imgh = (float)d_imgh[0], imgw = (float)d_imgw[0];
    for (int task = tid; task < 576; task += 256) {
        int ta = task >> 6, p2 = task & 63;
        int a_idx = (y * 64 + p2) * 9 + ta;
        int j = vpos[a_idx];
        if (j < 0) continue;
        float c0 = Ob[(2 * ta) * 64 + p2], c1 = Ob[(2 * ta + 1) * 64 + p2];
        float m = fmaxf(c0, c1);
        float e0 = expf(c0 - m), e1 = expf(c1 - m);
        float sden = e0 + e1;
        float p0v = e0 / sden, p1v = e1 / sden;
        out[OUT_CLS + (size_t)(b * KANC + j) * 2 + 0] = p0v;
        out[OUT_CLS + (size_t)(b * KANC + j) * 2 + 1] = p1v;
        float l0 = Ob[(18 + 4 * ta + 0) * 64 + p2];
        float l1 = Ob[(18 + 4 * ta + 1) * 64 + p2];
        float l2 = Ob[(18 + 4 * ta + 2) * 64 + p2];
        float l3 = Ob[(18 + 4 * ta + 3) * 64 + p2];
        out[OUT_REG + (size_t)(b * KANC + j) * 4 + 0] = l0;
        out[OUT_REG + (size_t)(b * KANC + j) * 4 + 1] = l1;
        out[OUT_REG + (size_t)(b * KANC + j) * 4 + 2] = l2;
        out[OUT_REG + (size_t)(b * KANC + j) * 4 + 3] = l3;
        float b0, b1, b2, b3; anchor_base(ta, b0, b1, b2, b3);
        float ay1 = b0 + 16.0f * y, ax1 = b1 + 16.0f * p2;
        float ay2 = b2 + 16.0f * y, ax2 = b3 + 16.0f * p2;
        float h = ay2 - ay1, w = ax2 - ax1;
        float cy = ay1 + 0.5f * h, cx = ax1 + 0.5f * w;
        float ncy = l0 * h + cy, ncx = l1 * w + cx;
        float nh = h * expf(l2), nw = w * expf(l3);
        float by1 = fminf(fmaxf(ncy - 0.5f * nh, 0.0f), imgh);
        float bx1 = fminf(fmaxf(ncx - 0.5f * nw, 0.0f), imgw);
        float by2 = fminf(fmaxf(ncy + 0.5f * nh, 0.0f), imgh);
        float bx2 = fminf(fmaxf(ncx + 0.5f * nw, 0.0f), imgw);
        boxes_ws[(size_t)(b * KANC + j) * 4 + 0] = by1;
        boxes_ws[(size_t)(b * KANC + j) * 4 + 1] = bx1;
        boxes_ws[(size_t)(b * KANC + j) * 4 + 2] = by2;
        boxes_ws[(size_t)(b * KANC + j) * 4 + 3] = bx2;
        float hs = by2 - by1, wsz = bx2 - bx1;
        u32 key = 0;
        if (hs >= 16.0f && wsz >= 16.0f) key = __float_as_uint(p1v) + 1u;  // +1: keep 0 as -inf sentinel
        keys_ws[b * KANC + j] = key;
    }
}

// ---------------- K3: exact top-2000 (3-level radix) + bitonic sort ----------------
__device__ __forceinline__ void suffix_scan(u32* suf, const u32* hist, int N, int tid) {
    for (int i = tid; i < N; i += 1024) suf[i] = hist[i];
    if (tid == 0) suf[N] = 0;
    __syncthreads();
    for (int off = 1; off < N; off <<= 1) {
        u32 add0 = 0, add1 = 0;
        int i0 = tid, i1 = tid + 1024;
        if (i0 < N) add0 = (i0 + off < N) ? suf[i0 + off] : 0;
        if (i1 < N) add1 = (i1 + off < N) ? suf[i1 + off] : 0;
        __syncthreads();
        if (i0 < N) suf[i0] += add0;
        if (i1 < N) suf[i1] += add1;
        __syncthreads();
    }
}

__global__ __launch_bounds__(1024) void k3_select(const u32* __restrict__ keys_ws,
                                                  const float* __restrict__ boxes_ws,
                                                  u32* __restrict__ topkey,
                                                  float* __restrict__ topbox) {
    int b = blockIdx.x, tid = threadIdx.x;
    const u32* keys = keys_ws + (size_t)b * KANC;
    __shared__ u32 hist[2048];
    __shared__ u32 suf[2049];
    __shared__ int Ps;
    __shared__ int cnt;
    __shared__ u64 sbuf[4096];

    // level 1: bits [30:20]
    for (int i = tid; i < 2048; i += 1024) hist[i] = 0;
    __syncthreads();
    for (int i = tid; i < KANC; i += 1024) atomicAdd(&hist[keys[i] >> 20], 1u);
    __syncthreads();
    suffix_scan(suf, hist, 2048, tid);
    if (tid == 0) Ps = 0;
    __syncthreads();
    for (int i = tid; i < 2048; i += 1024)
        if (suf[i] >= (u32)PRE && suf[i + 1] < (u32)PRE) Ps = i;
    __syncthreads();
    u32 P1 = (u32)Ps;
    u32 quota2 = (u32)PRE - suf[P1 + 1];
    __syncthreads();

    // level 2: bits [19:10] within bin P1
    for (int i = tid; i < 1024; i += 1024) hist[i] = 0;
    __syncthreads();
    for (int i = tid; i < KANC; i += 1024) {
        u32 k = keys[i];
        if ((k >> 20) == P1) atomicAdd(&hist[(k >> 10) & 1023u], 1u);
    }
    __syncthreads();
    suffix_scan(suf, hist, 1024, tid);
    if (tid == 0) Ps = 0;
    __syncthreads();
    for (int i = tid; i < 1024; i += 1024)
        if (suf[i] >= quota2 && suf[i + 1] < quota2) Ps = i;
    __syncthreads();
    u32 P2 = (u32)Ps;
    u32 quota3 = quota2 - suf[P2 + 1];
    __syncthreads();

    // level 3: bits [9:0] within prefix (P1<<10)|P2
    u32 pref = (P1 << 10) | P2;
    for (int i = tid; i < 1024; i += 1024) hist[i] = 0;
    __syncthreads();
    for (int i = tid; i < KANC; i += 1024) {
        u32 k = keys[i];
        if ((k >> 10) == pref) atomicAdd(&hist[k & 1023u], 1u);
    }
    __syncthreads();
    suffix_scan(suf, hist, 1024, tid);
    if (tid == 0) Ps = 0;
    __syncthreads();
    for (int i = tid; i < 1024; i += 1024)
        if (suf[i] >= quota3 && suf[i + 1] < quota3) Ps = i;
    __syncthreads();
    u32 P3 = (u32)Ps;
    u32 T = (P1 << 20) | (P2 << 10) | P3;
    u32 Tm = (T < 1u) ? 1u : T;

    // gather all keys >= Tm
    for (int i = tid; i < 4096; i += 1024) sbuf[i] = 0ull;
    if (tid == 0) cnt = 0;
    __syncthreads();
    for (int i = tid; i < KANC; i += 1024) {
        u32 k = keys[i];
        if (k >= Tm) {
            int pos = atomicAdd(&cnt, 1);
            if (pos < 4096)
                sbuf[pos] = ((u64)k << 32) | (u64)(0xFFFFFFFFu - (u32)i);
        }
    }
    __syncthreads();

    // bitonic sort descending, 4096 u64
    for (int k2 = 2; k2 <= 4096; k2 <<= 1) {
        for (int j2 = k2 >> 1; j2 > 0; j2 >>= 1) {
            for (int i = tid; i < 4096; i += 1024) {
                int ixj = i ^ j2;
                if (ixj > i) {
                    u64 va = sbuf[i], vb = sbuf[ixj];
                    bool descRegion = ((i & k2) == 0);
                    if (descRegion ? (va < vb) : (va > vb)) {
                        sbuf[i] = vb; sbuf[ixj] = va;
                    }
                }
            }
            __syncthreads();
        }
    }

    for (int i = tid; i < PREP; i += 1024) {
        u64 v = sbuf[i];
        u32 kk = (u32)(v >> 32);
        u32 j = 0xFFFFFFFFu - (u32)(v & 0xFFFFFFFFull);
        bool good = (i < PRE) && (kk != 0);
        topkey[b * PREP + i] = good ? kk : 0;
        float4 bx = make_float4(0.0f, 0.0f, 0.0f, 0.0f);
        if (good) bx = *(const float4*)&boxes_ws[(size_t)(b * KANC + j) * 4];
        *(float4*)&topbox[(size_t)(b * PREP + i) * 4] = bx;
    }
}

// ---------------- K4: NMS suppression bitmask ----------------
__global__ __launch_bounds__(64) void k4_mask(const float* __restrict__ topbox,
                                              u64* __restrict__ mask) {
    int jb = blockIdx.x, ib = blockIdx.y, b = blockIdx.z;
    int lane = threadIdx.x;
    float4 bi = *(const float4*)&topbox[(size_t)(b * PREP + ib * 64 + lane) * 4];
    float4 bj = *(const float4*)&topbox[(size_t)(b * PREP + jb * 64 + lane) * 4];
    float ai = (bi.z - bi.x) * (bi.w - bi.y);
    float aj = (bj.z - bj.x) * (bj.w - bj.y);
    u64 word = 0;
    for (int ii = 0; ii < 64; ii++) {
        float y1 = __shfl(bi.x, ii), x1 = __shfl(bi.y, ii);
        float y2 = __shfl(bi.z, ii), x2 = __shfl(bi.w, ii);
        float aii = __shfl(ai, ii);
        float yy1 = fmaxf(y1, bj.x), xx1 = fmaxf(x1, bj.y);
        float yy2 = fminf(y2, bj.z), xx2 = fminf(x2, bj.w);
        float inter = fmaxf(yy2 - yy1, 0.0f) * fmaxf(xx2 - xx1, 0.0f);
        float iou = inter / (aii + aj - inter + 1e-9f);
        u64 bal = __ballot(iou > 0.7f);
        if (lane == ii) word = bal;
    }
    mask[(size_t)(b * PREP + ib * 64 + lane) * 32 + jb] = word;
}

// ---------------- K5: sequential greedy scan + roi output ----------------
__global__ __launch_bounds__(64) void k5_nms(const u32* __restrict__ topkey,
                                             const float* __restrict__ topbox,
                                             const u64* __restrict__ mask,
                                             float* __restrict__ out) {
    int b = blockIdx.x;
    int lane = threadIdx.x;
    __shared__ u32 keys_s[PREP];
    __shared__ int kept[POST];
    for (int s = lane; s < PREP; s += 64) keys_s[s] = topkey[b * PREP + s];
    __syncthreads();
    const u64* mb = mask + (size_t)b * PREP * 32;
    u64 remv = 0;
    const int CH = 16;
    u64 bufA[CH], bufB[CH];
    auto loadRows = [&](u64* buf, int base) {
#pragma unroll
        for (int k = 0; k < CH; k++)
            buf[k] = (lane < 32) ? mb[(size_t)(base + k) * 32 + lane] : 0ull;
    };
    int nk = 0;
    bool done = false;
    loadRows(bufA, 0);
    for (int base = 0; base < PRE && !done; base += 2 * CH) {
        loadRows(bufB, base + CH);
#pragma unroll
        for (int k = 0; k < CH; k++) {
            int i = base + k;
            u64 w = __shfl(remv, i >> 6);
            if (!((w >> (i & 63)) & 1ull) && keys_s[i] != 0) {
                remv |= bufA[k];
                if (lane == 0) kept[nk] = i;
                nk++;
                if (nk == POST) { done = true; break; }
            }
        }
        if (!done && base + CH < PRE) {
            if (base + 2 * CH < PRE) loadRows(bufA, base + 2 * CH);
#pragma unroll
            for (int k = 0; k < CH; k++) {
                int i = base + CH + k;
                u64 w = __shfl(remv, i >> 6);
                if (!((w >> (i & 63)) & 1ull) && keys_s[i] != 0) {
                    remv |= bufB[k];
                    if (lane == 0) kept[nk] = i;
                    nk++;
                    if (nk == POST) { done = true; break; }
                }
            }
        }
    }
    __syncthreads();
    for (int s = lane; s < POST; s += 64) {
        float4 bx = make_float4(0.0f, 0.0f, 0.0f, 0.0f);
        if (s < nk) bx = *(const float4*)&topbox[(size_t)(b * PREP + kept[s]) * 4];
        *(float4*)&out[OUT_ROI + (size_t)(b * POST + s) * 4] = bx;
        out[OUT_RID + b * POST + s] = (float)b;
    }
}

extern "C" void kernel_launch(void* const* d_in, const int* in_sizes, int n_in,
                              void* d_out, int out_size, void* d_ws, size_t ws_size,
                              hipStream_t stream) {
    (void)in_sizes; (void)n_in; (void)out_size; (void)ws_size;
    const float* feat    = (const float*)d_in[0];
    const float* share_w = (const float*)d_in[1];
    const float* share_b = (const float*)d_in[2];
    const float* cls_w   = (const float*)d_in[3];
    const float* cls_b   = (const float*)d_in[4];
    const float* reg_w   = (const float*)d_in[5];
    const float* reg_b   = (const float*)d_in[6];
    const int*   imgh    = (const int*)d_in[7];
    const int*   imgw    = (const int*)d_in[8];
    float* out = (float*)d_out;
    char* ws = (char*)d_ws;
    float* shared_ws = (float*)(ws + WS_SHARED);
    int*   vpos      = (int*)(ws + WS_VPOS);
    float* boxes_ws  = (float*)(ws + WS_BOXES);
    u32*   keys_ws   = (u32*)(ws + WS_KEYS);
    float* topbox    = (float*)(ws + WS_TOPBOX);
    u32*   topkey    = (u32*)(ws + WS_TOPKEY);
    u64*   mask      = (u64*)(ws + WS_MASK);

    k0_anchors<<<1, 1024, 0, stream>>>(out, vpos, imgh, imgw);
    k1_conv<<<dim3(128, 8), 256, 0, stream>>>(feat, share_w, share_b, shared_ws);
    k2_heads<<<128, 256, 0, stream>>>(shared_ws, cls_w, cls_b, reg_w, reg_b, vpos,
                                      out, boxes_ws, keys_ws, imgh, imgw);
    k3_select<<<2, 1024, 0, stream>>>(keys_ws, boxes_ws, topkey, topbox);
    k4_mask<<<dim3(32, 32, 2), 64, 0, stream>>>(topbox, mask);
    k5_nms<<<2, 64, 0, stream>>>(topkey, topbox, mask, out);
}

// Round 2
// 870.034 us; speedup vs baseline: 1.7203x; 1.7203x over previous
//
#include <hip/hip_runtime.h>
#include <math.h>

typedef unsigned int u32;
typedef unsigned long long u64;
typedef unsigned short ushort_t;

typedef __attribute__((ext_vector_type(8))) short short8;
typedef __attribute__((ext_vector_type(4))) float f32x4;

#define KANC 18376
#define PRE 2000
#define PREP 2048
#define POST 300

#define OUT_CLS 0
#define OUT_REG 73504
#define OUT_ROI 220512
#define OUT_RID 222912
#define OUT_ANC 223512

// ws byte offsets
#define WS_NHWC   0u
#define WS_FT     16777216u
#define WS_W3     41943040u
#define WS_VPOS   56098816u
#define WS_BOXES  56246272u
#define WS_KEYS   56834304u
#define WS_TOPBOX 56981312u
#define WS_TOPKEY 57046848u
#define WS_MASK   57063232u

// k1 LDS layout (ushort units)
#define A_SPL 10560   // 4*66*40
#define B_OFF 31680   // 3*A_SPL
#define B_SPL 5120    // 128*40
#define LDS_TOT 47040 // B_OFF + 3*B_SPL  (94080 bytes)

__device__ __forceinline__ ushort_t f2bf(float f) {
    u32 u = __float_as_uint(f);
    u32 r = (u + 0x7FFFu + ((u >> 16) & 1u)) >> 16;
    return (ushort_t)r;
}
__device__ __forceinline__ float bf2f(ushort_t h) {
    return __uint_as_float(((u32)h) << 16);
}

__device__ __forceinline__ void anchor_base(int t, float& y1, float& x1, float& y2, float& x2) {
    const double ratios[3] = {0.5, 1.0, 2.0};
    const double scales[3] = {8.0, 16.0, 32.0};
    double r = ratios[t / 3], s = scales[t % 3];
    double h = 16.0 * s * sqrt(r);
    double w = 16.0 * s * sqrt(1.0 / r);
    y1 = (float)(8.0 - h * 0.5);
    x1 = (float)(8.0 - w * 0.5);
    y2 = (float)(8.0 + h * 0.5);
    x2 = (float)(8.0 + w * 0.5);
}

// ---------------- T1: feat NCHW fp32 -> ft[s][b][y][x][ci] bf16x3 ----------------
__global__ __launch_bounds__(256) void t1_feat(const float* __restrict__ feat,
                                               ushort_t* __restrict__ ft) {
    int by = blockIdx.y;            // b*64 + y
    int b = by >> 6, y = by & 63;
    int ci0 = blockIdx.x * 64;
    int tid = threadIdx.x;
    __shared__ float tile[64 * 65];
    for (int it = 0; it < 16; it++) {
        int idx = it * 256 + tid;
        int ci = idx >> 6, x = idx & 63;
        tile[ci * 65 + x] = feat[((size_t)(b * 512 + ci0 + ci) * 64 + y) * 64 + x];
    }
    __syncthreads();
    for (int it = 0; it < 16; it++) {
        int idx = it * 256 + tid;
        int x = idx >> 6, ci = idx & 63;
        float v = tile[ci * 65 + x];
        ushort_t hi = f2bf(v);
        float r1 = v - bf2f(hi);
        ushort_t mid = f2bf(r1);
        float r2 = r1 - bf2f(mid);
        ushort_t lo = f2bf(r2);
        size_t base = ((size_t)(b * 64 + y) * 64 + x) * 512 + ci0 + ci;
        const size_t spl = (size_t)2 * 64 * 64 * 512;
        ft[base] = hi;
        ft[base + spl] = mid;
        ft[base + 2 * spl] = lo;
    }
}

// ---------------- T2: weights OIHW fp32 -> w3[s][kykx][co][ci] bf16x3 ----------------
__global__ __launch_bounds__(256) void t2_wgt(const float* __restrict__ w,
                                              ushort_t* __restrict__ w3) {
    int tg = blockIdx.x * 256 + threadIdx.x;   // 262144
    int co = tg >> 9, ci = tg & 511;
    const size_t spl = (size_t)9 * 512 * 512;
    for (int kk = 0; kk < 9; kk++) {
        float v = w[(size_t)(co * 512 + ci) * 9 + kk];
        ushort_t hi = f2bf(v);
        float r1 = v - bf2f(hi);
        ushort_t mid = f2bf(r1);
        float r2 = r1 - bf2f(mid);
        ushort_t lo = f2bf(r2);
        size_t base = ((size_t)kk * 512 + co) * 512 + ci;
        w3[base] = hi;
        w3[base + spl] = mid;
        w3[base + 2 * spl] = lo;
    }
}

// ---------------- K0: anchors + valid-position map ----------------
__global__ __launch_bounds__(1024) void k0_anchors(float* out, int* vpos,
                                                   const int* d_imgh, const int* d_imgw) {
    int tid = threadIdx.x;
    float imgh = (float)d_imgh[0], imgw = (float)d_imgw[0];
    __shared__ int cnt[1024];
    int base = tid * 36;
    int c = 0;
    for (int k = 0; k < 36; k++) {
        int a = base + k;
        int t = a % 9; int pix = a / 9; int x = pix & 63; int y = pix >> 6;
        float b0, b1, b2, b3; anchor_base(t, b0, b1, b2, b3);
        float a0 = b0 + 16.0f * y, a1 = b1 + 16.0f * x;
        float a2 = b2 + 16.0f * y, a3 = b3 + 16.0f * x;
        out[OUT_ANC + a * 4 + 0] = a0;
        out[OUT_ANC + a * 4 + 1] = a1;
        out[OUT_ANC + a * 4 + 2] = a2;
        out[OUT_ANC + a * 4 + 3] = a3;
        if (a0 >= 0.0f && a1 >= 0.0f && a2 <= imgh && a3 <= imgw) c++;
    }
    cnt[tid] = c;
    __syncthreads();
    for (int off = 1; off < 1024; off <<= 1) {
        int v = cnt[tid];
        int u = (tid >= off) ? cnt[tid - off] : 0;
        __syncthreads();
        cnt[tid] = v + u;
        __syncthreads();
    }
    int j = (tid == 0) ? 0 : cnt[tid - 1];
    for (int k = 0; k < 36; k++) {
        int a = base + k;
        int t = a % 9; int pix = a / 9; int x = pix & 63; int y = pix >> 6;
        float b0, b1, b2, b3; anchor_base(t, b0, b1, b2, b3);
        float a0 = b0 + 16.0f * y, a1 = b1 + 16.0f * x;
        float a2 = b2 + 16.0f * y, a3 = b3 + 16.0f * x;
        bool ok = (a0 >= 0.0f && a1 >= 0.0f && a2 <= imgh && a3 <= imgw);
        vpos[a] = ok ? j : -1;
        if (ok) j++;
    }
}

// ---------------- K1: 3x3 conv 512->512 via bf16x3 MFMA implicit GEMM ----------------
__global__ __launch_bounds__(256, 1) void k1_conv(const ushort_t* __restrict__ ft,
                                                  const ushort_t* __restrict__ w3,
                                                  const float* __restrict__ bias,
                                                  float* __restrict__ nhwc) {
    extern __shared__ ushort_t lds16[];
    int tid = threadIdx.x;
    int bid = blockIdx.x;
    int nt = (bid & 7) >> 1;
    int mt = ((bid >> 3) << 1) | (bid & 1);
    int b = mt >> 5;
    int y0 = (mt & 31) << 1;
    int nb = nt << 7;

    int lane = tid & 63;
    int w = tid >> 6;                 // wave 0..3
    int dy = w & 1;                   // pixel row within tile
    int n_off = (w >> 1) * 64;
    int mlane = lane & 15;
    int quad = lane >> 4;
    int koff8 = quad * 8;

    const size_t FT_SPL = (size_t)2 * 64 * 64 * 512;
    const size_t W3_SPL = (size_t)9 * 512 * 512;

    // staging thread mapping
    int sx = tid >> 2;               // 0..63
    int sq = tid & 3;                // 0..3

    f32x4 acc[4][4];
#pragma unroll
    for (int mi = 0; mi < 4; mi++)
#pragma unroll
        for (int ni = 0; ni < 4; ni++) {
            acc[mi][ni][0] = 0.f; acc[mi][ni][1] = 0.f;
            acc[mi][ni][2] = 0.f; acc[mi][ni][3] = 0.f;
        }

    // bias preload (per ni, lane-varying over 16 co)
    float bv[4];
#pragma unroll
    for (int ni = 0; ni < 4; ni++) bv[ni] = bias[nb + n_off + ni * 16 + mlane];

    // zero x-halo columns (xi = 0 and 65), persists across ci-tiles
    if (tid < 96) {
        int slot = tid >> 2, q = tid & 3;
        int s = slot >> 3, rem = slot & 7, r = rem >> 1, side = rem & 1;
        int xi = side * 65;
        uint4 z = make_uint4(0, 0, 0, 0);
        *(uint4*)&lds16[s * A_SPL + (r * 66 + xi) * 40 + q * 8] = z;
    }

    uint4 pbA[12];   // A patch prefetch: (r 0..3, s 0..2) -> one uint4 per thread
    uint4 pbB[6];    // B chunk prefetch

    auto loadA = [&](int ct) {
#pragma unroll
        for (int r = 0; r < 4; r++) {
            int yy = y0 - 1 + r;
            bool valid = (yy >= 0 && yy < 64);
            size_t rowbase = ((size_t)(b * 64 + (valid ? yy : 0)) * 64 + sx) * 512 + ct * 32 + sq * 8;
#pragma unroll
            for (int s = 0; s < 3; s++) {
                uint4 v = make_uint4(0, 0, 0, 0);
                if (valid) v = *(const uint4*)&ft[rowbase + (size_t)s * FT_SPL];
                pbA[r * 3 + s] = v;
            }
        }
    };
    auto loadB = [&](int ct, int kykx) {
#pragma unroll
        for (int i = 0; i < 6; i++) {
            int ii = i * 256 + tid;
            int s = ii >> 9, rem = ii & 511;
            int co = rem >> 2, q = rem & 3;
            pbB[i] = *(const uint4*)&w3[(size_t)s * W3_SPL +
                                        ((size_t)kykx * 512 + nb + co) * 512 + ct * 32 + q * 8];
        }
    };
    auto writeA = [&]() {
#pragma unroll
        for (int r = 0; r < 4; r++)
#pragma unroll
            for (int s = 0; s < 3; s++)
                *(uint4*)&lds16[s * A_SPL + (r * 66 + sx + 1) * 40 + sq * 8] = pbA[r * 3 + s];
    };
    auto writeB = [&]() {
#pragma unroll
        for (int i = 0; i < 6; i++) {
            int ii = i * 256 + tid;
            int s = ii >> 9, rem = ii & 511;
            int co = rem >> 2, q = rem & 3;
            *(uint4*)&lds16[B_OFF + s * B_SPL + co * 40 + q * 8] = pbB[i];
        }
    };

    loadA(0);
    loadB(0, 0);

    for (int ct = 0; ct < 16; ct++) {
        __syncthreads();
        writeA();
        writeB();
        __syncthreads();
        if (ct < 15) loadA(ct + 1);   // hidden behind this ct's 9 taps
        loadB(ct, 1);

        for (int kykx = 0; kykx < 9; kykx++) {
            int ky = kykx / 3, kx = kykx - ky * 3;
            // fragment loads
            short8 af[3][4], bf[3][4];
            int arow = (dy + ky) * 66;
#pragma unroll
            for (int s = 0; s < 3; s++) {
                int ab = s * A_SPL + (arow + mlane + kx) * 40 + koff8;
#pragma unroll
                for (int mi = 0; mi < 4; mi++)
                    af[s][mi] = *(const short8*)&lds16[ab + mi * 640];
                int bb = B_OFF + s * B_SPL + (n_off + mlane) * 40 + koff8;
#pragma unroll
                for (int ni = 0; ni < 4; ni++)
                    bf[s][ni] = *(const short8*)&lds16[bb + ni * 640];
            }
            // 6 split-products
#pragma unroll
            for (int t = 0; t < 6; t++) {
                const int sa_t[6] = {0, 0, 1, 0, 1, 2};
                const int sb_t[6] = {0, 1, 0, 2, 1, 0};
                int sa = sa_t[t], sb = sb_t[t];
#pragma unroll
                for (int mi = 0; mi < 4; mi++)
#pragma unroll
                    for (int ni = 0; ni < 4; ni++)
                        acc[mi][ni] = __builtin_amdgcn_mfma_f32_16x16x32_bf16(
                            af[sa][mi], bf[sb][ni], acc[mi][ni], 0, 0, 0);
            }

            if (kykx < 8) {
                __syncthreads();
                writeB();
                __syncthreads();
                int next = kykx + 2;
                if (next <= 8) loadB(ct, next);
                else if (ct < 15) loadB(ct + 1, 0);
            }
        }
    }

    // epilogue: bias + relu, write NHWC fp32
    int y = y0 + dy;
#pragma unroll
    for (int mi = 0; mi < 4; mi++) {
#pragma unroll
        for (int r = 0; r < 4; r++) {
            int x = mi * 16 + quad * 4 + r;
            size_t obase = ((size_t)(b * 64 + y) * 64 + x) * 512;
#pragma unroll
            for (int ni = 0; ni < 4; ni++) {
                int co = nb + n_off + ni * 16 + mlane;
                float v = acc[mi][ni][r] + bv[ni];
                nhwc[obase + co] = fmaxf(v, 0.0f);
            }
        }
    }
}

// ---------------- K2: 1x1 heads + softmax + decode + score keys (NHWC input) ----------------
__global__ __launch_bounds__(256) void k2_heads(const float* __restrict__ nhwc,
                                                const float* __restrict__ cls_w,
                                                const float* __restrict__ cls_b,
                                                const float* __restrict__ reg_w,
                                                const float* __restrict__ reg_b,
                                                const int* __restrict__ vpos,
                                                float* __restrict__ out,
                                                float* __restrict__ boxes_ws,
                                                u32* __restrict__ keys_ws,
                                                const int* d_imgh, const int* d_imgw) {
    int row = blockIdx.x;           // b*64 + y
    int b = row >> 6, y = row & 63;
    int tid = threadIdx.x;
    __shared__ float Al[64 * 65];   // [p][ci], pad 65
    __shared__ float Wl[54 * 64];   // [o][ci]
    __shared__ float Ob[54 * 64];   // [o][p]
    int p = tid & 63, g = tid >> 6;
    int o0 = g * 14;
    int no = (g == 3) ? 12 : 14;
    float acc[14];
#pragma unroll
    for (int i = 0; i < 14; i++) acc[i] = 0.0f;
    for (int cib = 0; cib < 512; cib += 64) {
        for (int s = tid; s < 4096; s += 256) {
            int kk = s & 63, pp = s >> 6;
            Al[pp * 65 + kk] = nhwc[((size_t)(b * 64 + y) * 64 + pp) * 512 + cib + kk];
        }
        for (int s = tid; s < 54 * 64; s += 256) {
            int o = s >> 6, kk = s & 63;
            Wl[s] = (o < 18) ? cls_w[o * 512 + cib + kk] : reg_w[(o - 18) * 512 + cib + kk];
        }
        __syncthreads();
        for (int kk = 0; kk < 64; kk++) {
            float a = Al[p * 65 + kk];
#pragma unroll
            for (int oo = 0; oo < 14; oo++)
                if (oo < no) acc[oo] += a * Wl[(o0 + oo) * 64 + kk];
        }
        __syncthreads();
    }
#pragma unroll
    for (int oo = 0; oo < 14; oo++)
        if (oo < no) {
            int o = o0 + oo;
            float bvv = (o < 18) ? cls_b[o] : reg_b[o - 18];
            Ob[o * 64 + p] = acc[oo] + bvv;
        }
    __syncthreads();
    float imgh = (float)d_imgh[0], imgw = (float)d_imgw[0];
    for (int task = tid; task < 576; task += 256) {
        int ta = task >> 6, p2 = task & 63;
        int a_idx = (y * 64 + p2) * 9 + ta;
        int j = vpos[a_idx];
        if (j < 0) continue;
        float c0 = Ob[(2 * ta) * 64 + p2], c1 = Ob[(2 * ta + 1) * 64 + p2];
        float m = fmaxf(c0, c1);
        float e0 = expf(c0 - m), e1 = expf(c1 - m);
        float sden = e0 + e1;
        float p0v = e0 / sden, p1v = e1 / sden;
        out[OUT_CLS + (size_t)(b * KANC + j) * 2 + 0] = p0v;
        out[OUT_CLS + (size_t)(b * KANC + j) * 2 + 1] = p1v;
        float l0 = Ob[(18 + 4 * ta + 0) * 64 + p2];
        float l1 = Ob[(18 + 4 * ta + 1) * 64 + p2];
        float l2 = Ob[(18 + 4 * ta + 2) * 64 + p2];
        float l3 = Ob[(18 + 4 * ta + 3) * 64 + p2];
        out[OUT_REG + (size_t)(b * KANC + j) * 4 + 0] = l0;
        out[OUT_REG + (size_t)(b * KANC + j) * 4 + 1] = l1;
        out[OUT_REG + (size_t)(b * KANC + j) * 4 + 2] = l2;
        out[OUT_REG + (size_t)(b * KANC + j) * 4 + 3] = l3;
        float b0, b1, b2, b3; anchor_base(ta, b0, b1, b2, b3);
        float ay1 = b0 + 16.0f * y, ax1 = b1 + 16.0f * p2;
        float ay2 = b2 + 16.0f * y, ax2 = b3 + 16.0f * p2;
        float h = ay2 - ay1, wdt = ax2 - ax1;
        float cy = ay1 + 0.5f * h, cx = ax1 + 0.5f * wdt;
        float ncy = l0 * h + cy, ncx = l1 * wdt + cx;
        float nh = h * expf(l2), nw = wdt * expf(l3);
        float by1 = fminf(fmaxf(ncy - 0.5f * nh, 0.0f), imgh);
        float bx1 = fminf(fmaxf(ncx - 0.5f * nw, 0.0f), imgw);
        float by2 = fminf(fmaxf(ncy + 0.5f * nh, 0.0f), imgh);
        float bx2 = fminf(fmaxf(ncx + 0.5f * nw, 0.0f), imgw);
        boxes_ws[(size_t)(b * KANC + j) * 4 + 0] = by1;
        boxes_ws[(size_t)(b * KANC + j) * 4 + 1] = bx1;
        boxes_ws[(size_t)(b * KANC + j) * 4 + 2] = by2;
        boxes_ws[(size_t)(b * KANC + j) * 4 + 3] = bx2;
        float hs = by2 - by1, wsz = bx2 - bx1;
        u32 key = 0;
        if (hs >= 16.0f && wsz >= 16.0f) key = __float_as_uint(p1v) + 1u;
        keys_ws[b * KANC + j] = key;
    }
}

// ---------------- K3: exact top-2000 (3-level radix) + bitonic sort ----------------
__device__ __forceinline__ void suffix_scan(u32* suf, const u32* hist, int N, int tid) {
    for (int i = tid; i < N; i += 1024) suf[i] = hist[i];
    if (tid == 0) suf[N] = 0;
    __syncthreads();
    for (int off = 1; off < N; off <<= 1) {
        u32 add0 = 0, add1 = 0;
        int i0 = tid, i1 = tid + 1024;
        if (i0 < N) add0 = (i0 + off < N) ? suf[i0 + off] : 0;
        if (i1 < N) add1 = (i1 + off < N) ? suf[i1 + off] : 0;
        __syncthreads();
        if (i0 < N) suf[i0] += add0;
        if (i1 < N) suf[i1] += add1;
        __syncthreads();
    }
}

__global__ __launch_bounds__(1024) void k3_select(const u32* __restrict__ keys_ws,
                                                  const float* __restrict__ boxes_ws,
                                                  u32* __restrict__ topkey,
                                                  float* __restrict__ topbox) {
    int b = blockIdx.x, tid = threadIdx.x;
    const u32* keys = keys_ws + (size_t)b * KANC;
    __shared__ u32 hist[2048];
    __shared__ u32 suf[2049];
    __shared__ int Ps;
    __shared__ int cnt;
    __shared__ u64 sbuf[4096];

    for (int i = tid; i < 2048; i += 1024) hist[i] = 0;
    __syncthreads();
    for (int i = tid; i < KANC; i += 1024) atomicAdd(&hist[keys[i] >> 20], 1u);
    __syncthreads();
    suffix_scan(suf, hist, 2048, tid);
    if (tid == 0) Ps = 0;
    __syncthreads();
    for (int i = tid; i < 2048; i += 1024)
        if (suf[i] >= (u32)PRE && suf[i + 1] < (u32)PRE) Ps = i;
    __syncthreads();
    u32 P1 = (u32)Ps;
    u32 quota2 = (u32)PRE - suf[P1 + 1];
    __syncthreads();

    for (int i = tid; i < 1024; i += 1024) hist[i] = 0;
    __syncthreads();
    for (int i = tid; i < KANC; i += 1024) {
        u32 k = keys[i];
        if ((k >> 20) == P1) atomicAdd(&hist[(k >> 10) & 1023u], 1u);
    }
    __syncthreads();
    suffix_scan(suf, hist, 1024, tid);
    if (tid == 0) Ps = 0;
    __syncthreads();
    for (int i = tid; i < 1024; i += 1024)
        if (suf[i] >= quota2 && suf[i + 1] < quota2) Ps = i;
    __syncthreads();
    u32 P2 = (u32)Ps;
    u32 quota3 = quota2 - suf[P2 + 1];
    __syncthreads();

    u32 pref = (P1 << 10) | P2;
    for (int i = tid; i < 1024; i += 1024) hist[i] = 0;
    __syncthreads();
    for (int i = tid; i < KANC; i += 1024) {
        u32 k = keys[i];
        if ((k >> 10) == pref) atomicAdd(&hist[k & 1023u], 1u);
    }
    __syncthreads();
    suffix_scan(suf, hist, 1024, tid);
    if (tid == 0) Ps = 0;
    __syncthreads();
    for (int i = tid; i < 1024; i += 1024)
        if (suf[i] >= quota3 && suf[i + 1] < quota3) Ps = i;
    __syncthreads();
    u32 P3 = (u32)Ps;
    u32 T = (P1 << 20) | (P2 << 10) | P3;
    u32 Tm = (T < 1u) ? 1u : T;

    for (int i = tid; i < 4096; i += 1024) sbuf[i] = 0ull;
    if (tid == 0) cnt = 0;
    __syncthreads();
    for (int i = tid; i < KANC; i += 1024) {
        u32 k = keys[i];
        if (k >= Tm) {
            int pos = atomicAdd(&cnt, 1);
            if (pos < 4096)
                sbuf[pos] = ((u64)k << 32) | (u64)(0xFFFFFFFFu - (u32)i);
        }
    }
    __syncthreads();

    for (int k2 = 2; k2 <= 4096; k2 <<= 1) {
        for (int j2 = k2 >> 1; j2 > 0; j2 >>= 1) {
            for (int i = tid; i < 4096; i += 1024) {
                int ixj = i ^ j2;
                if (ixj > i) {
                    u64 va = sbuf[i], vb = sbuf[ixj];
                    bool descRegion = ((i & k2) == 0);
                    if (descRegion ? (va < vb) : (va > vb)) {
                        sbuf[i] = vb; sbuf[ixj] = va;
                    }
                }
            }
            __syncthreads();
        }
    }

    for (int i = tid; i < PREP; i += 1024) {
        u64 v = sbuf[i];
        u32 kk = (u32)(v >> 32);
        u32 j = 0xFFFFFFFFu - (u32)(v & 0xFFFFFFFFull);
        bool good = (i < PRE) && (kk != 0);
        topkey[b * PREP + i] = good ? kk : 0;
        float4 bx = make_float4(0.0f, 0.0f, 0.0f, 0.0f);
        if (good) bx = *(const float4*)&boxes_ws[(size_t)(b * KANC + j) * 4];
        *(float4*)&topbox[(size_t)(b * PREP + i) * 4] = bx;
    }
}

// ---------------- K4: NMS suppression bitmask ----------------
__global__ __launch_bounds__(64) void k4_mask(const float* __restrict__ topbox,
                                              u64* __restrict__ mask) {
    int jb = blockIdx.x, ib = blockIdx.y, b = blockIdx.z;
    int lane = threadIdx.x;
    float4 bi = *(const float4*)&topbox[(size_t)(b * PREP + ib * 64 + lane) * 4];
    float4 bj = *(const float4*)&topbox[(size_t)(b * PREP + jb * 64 + lane) * 4];
    float ai = (bi.z - bi.x) * (bi.w - bi.y);
    float aj = (bj.z - bj.x) * (bj.w - bj.y);
    u64 word = 0;
    for (int ii = 0; ii < 64; ii++) {
        float y1 = __shfl(bi.x, ii), x1 = __shfl(bi.y, ii);
        float y2 = __shfl(bi.z, ii), x2 = __shfl(bi.w, ii);
        float aii = __shfl(ai, ii);
        float yy1 = fmaxf(y1, bj.x), xx1 = fmaxf(x1, bj.y);
        float yy2 = fminf(y2, bj.z), xx2 = fminf(x2, bj.w);
        float inter = fmaxf(yy2 - yy1, 0.0f) * fmaxf(xx2 - xx1, 0.0f);
        float iou = inter / (aii + aj - inter + 1e-9f);
        u64 bal = __ballot(iou > 0.7f);
        if (lane == ii) word = bal;
    }
    mask[(size_t)(b * PREP + ib * 64 + lane) * 32 + jb] = word;
}

// ---------------- K5: sequential greedy scan + roi output ----------------
__global__ __launch_bounds__(64) void k5_nms(const u32* __restrict__ topkey,
                                             const float* __restrict__ topbox,
                                             const u64* __restrict__ mask,
                                             float* __restrict__ out) {
    int b = blockIdx.x;
    int lane = threadIdx.x;
    __shared__ u32 keys_s[PREP];
    __shared__ int kept[POST];
    for (int s = lane; s < PREP; s += 64) keys_s[s] = topkey[b * PREP + s];
    __syncthreads();
    const u64* mb = mask + (size_t)b * PREP * 32;
    u64 remv = 0;
    const int CH = 16;
    u64 bufA[CH], bufB[CH];
    auto loadRows = [&](u64* buf, int base) {
#pragma unroll
        for (int k = 0; k < CH; k++)
            buf[k] = (lane < 32) ? mb[(size_t)(base + k) * 32 + lane] : 0ull;
    };
    int nk = 0;
    bool done = false;
    loadRows(bufA, 0);
    for (int base = 0; base < PRE && !done; base += 2 * CH) {
        loadRows(bufB, base + CH);
#pragma unroll
        for (int k = 0; k < CH; k++) {
            int i = base + k;
            u64 wv = __shfl(remv, i >> 6);
            if (!((wv >> (i & 63)) & 1ull) && keys_s[i] != 0) {
                remv |= bufA[k];
                if (lane == 0) kept[nk] = i;
                nk++;
                if (nk == POST) { done = true; break; }
            }
        }
        if (!done && base + CH < PRE) {
            if (base + 2 * CH < PRE) loadRows(bufA, base + 2 * CH);
#pragma unroll
            for (int k = 0; k < CH; k++) {
                int i = base + CH + k;
                u64 wv = __shfl(remv, i >> 6);
                if (!((wv >> (i & 63)) & 1ull) && keys_s[i] != 0) {
                    remv |= bufB[k];
                    if (lane == 0) kept[nk] = i;
                    nk++;
                    if (nk == POST) { done = true; break; }
                }
            }
        }
    }
    __syncthreads();
    for (int s = lane; s < POST; s += 64) {
        float4 bx = make_float4(0.0f, 0.0f, 0.0f, 0.0f);
        if (s < nk) bx = *(const float4*)&topbox[(size_t)(b * PREP + kept[s]) * 4];
        *(float4*)&out[OUT_ROI + (size_t)(b * POST + s) * 4] = bx;
        out[OUT_RID + b * POST + s] = (float)b;
    }
}

extern "C" void kernel_launch(void* const* d_in, const int* in_sizes, int n_in,
                              void* d_out, int out_size, void* d_ws, size_t ws_size,
                              hipStream_t stream) {
    (void)in_sizes; (void)n_in; (void)out_size; (void)ws_size;
    const float* feat    = (const float*)d_in[0];
    const float* share_w = (const float*)d_in[1];
    const float* share_b = (const float*)d_in[2];
    const float* cls_w   = (const float*)d_in[3];
    const float* cls_b   = (const float*)d_in[4];
    const float* reg_w   = (const float*)d_in[5];
    const float* reg_b   = (const float*)d_in[6];
    const int*   imgh    = (const int*)d_in[7];
    const int*   imgw    = (const int*)d_in[8];
    float* out = (float*)d_out;
    char* ws = (char*)d_ws;
    float*     nhwc   = (float*)(ws + WS_NHWC);
    ushort_t*  ft     = (ushort_t*)(ws + WS_FT);
    ushort_t*  w3     = (ushort_t*)(ws + WS_W3);
    int*       vpos   = (int*)(ws + WS_VPOS);
    float*     boxes  = (float*)(ws + WS_BOXES);
    u32*       keys   = (u32*)(ws + WS_KEYS);
    float*     topbox = (float*)(ws + WS_TOPBOX);
    u32*       topkey = (u32*)(ws + WS_TOPKEY);
    u64*       mask   = (u64*)(ws + WS_MASK);

    static bool attr_set = false;
    hipFuncSetAttribute((const void*)k1_conv,
                        hipFuncAttributeMaxDynamicSharedMemorySize, LDS_TOT * 2);
    (void)attr_set;

    t1_feat<<<dim3(8, 128), 256, 0, stream>>>(feat, ft);
    t2_wgt<<<1024, 256, 0, stream>>>(share_w, w3);
    k0_anchors<<<1, 1024, 0, stream>>>(out, vpos, imgh, imgw);
    k1_conv<<<256, 256, LDS_TOT * 2, stream>>>(ft, w3, share_b, nhwc);
    k2_heads<<<128, 256, 0, stream>>>(nhwc, cls_w, cls_b, reg_w, reg_b, vpos,
                                      out, boxes, keys, imgh, imgw);
    k3_select<<<2, 1024, 0, stream>>>(keys, boxes, topkey, topbox);
    k4_mask<<<dim3(32, 32, 2), 64, 0, stream>>>(topbox, mask);
    k5_nms<<<2, 64, 0, stream>>>(topkey, topbox, mask, out);
}

// Round 4
// 725.779 us; speedup vs baseline: 2.0623x; 1.1988x over previous
//
#include <hip/hip_runtime.h>
#include <math.h>

typedef unsigned int u32;
typedef unsigned long long u64;
typedef unsigned short ushort_t;

typedef __attribute__((ext_vector_type(8))) short short8;
typedef __attribute__((ext_vector_type(4))) float f32x4;

template <int N> struct Ic { static constexpr int value = N; };

#define KANC 18376
#define PRE 2000
#define PREP 2048
#define POST 300

#define OUT_CLS 0
#define OUT_REG 73504
#define OUT_ROI 220512
#define OUT_RID 222912
#define OUT_ANC 223512

// ws byte offsets
#define WS_NHWC   0u
#define WS_FT     16777216u
#define WS_W3     41943040u
#define WS_VPOS   56098816u
#define WS_BOXES  56246272u
#define WS_KEYS   56834304u
#define WS_TOPBOX 56981312u
#define WS_TOPKEY 57046848u
#define WS_MASK   57063232u

// k1 LDS: A only, 3 splits x 3 rows x 66 xi x (32ci pad to 40)
#define A_SPL2 7920   // ushorts per split (3*66*40)

__device__ __forceinline__ ushort_t f2bf(float f) {
    u32 u = __float_as_uint(f);
    u32 r = (u + 0x7FFFu + ((u >> 16) & 1u)) >> 16;
    return (ushort_t)r;
}
__device__ __forceinline__ float bf2f(ushort_t h) {
    return __uint_as_float(((u32)h) << 16);
}

__device__ __forceinline__ void anchor_base(int t, float& y1, float& x1, float& y2, float& x2) {
    const double ratios[3] = {0.5, 1.0, 2.0};
    const double scales[3] = {8.0, 16.0, 32.0};
    double r = ratios[t / 3], s = scales[t % 3];
    double h = 16.0 * s * sqrt(r);
    double w = 16.0 * s * sqrt(1.0 / r);
    y1 = (float)(8.0 - h * 0.5);
    x1 = (float)(8.0 - w * 0.5);
    y2 = (float)(8.0 + h * 0.5);
    x2 = (float)(8.0 + w * 0.5);
}

// ---------------- T1: feat NCHW fp32 -> ft[s][b][y][x][ci] bf16x3 ----------------
__global__ __launch_bounds__(256) void t1_feat(const float* __restrict__ feat,
                                               ushort_t* __restrict__ ft) {
    int by = blockIdx.y;            // b*64 + y
    int b = by >> 6, y = by & 63;
    int ci0 = blockIdx.x * 64;
    int tid = threadIdx.x;
    __shared__ float tile[64 * 65];
    for (int it = 0; it < 16; it++) {
        int idx = it * 256 + tid;
        int ci = idx >> 6, x = idx & 63;
        tile[ci * 65 + x] = feat[((size_t)(b * 512 + ci0 + ci) * 64 + y) * 64 + x];
    }
    __syncthreads();
    for (int it = 0; it < 16; it++) {
        int idx = it * 256 + tid;
        int x = idx >> 6, ci = idx & 63;
        float v = tile[ci * 65 + x];
        ushort_t hi = f2bf(v);
        float r1 = v - bf2f(hi);
        ushort_t mid = f2bf(r1);
        float r2 = r1 - bf2f(mid);
        ushort_t lo = f2bf(r2);
        size_t base = ((size_t)(b * 64 + y) * 64 + x) * 512 + ci0 + ci;
        const size_t spl = (size_t)2 * 64 * 64 * 512;
        ft[base] = hi;
        ft[base + spl] = mid;
        ft[base + 2 * spl] = lo;
    }
}

// ---------------- T2: weights OIHW fp32 -> w3[s][kykx][co][ci] bf16x3 ----------------
__global__ __launch_bounds__(256) void t2_wgt(const float* __restrict__ w,
                                              ushort_t* __restrict__ w3) {
    int tg = blockIdx.x * 256 + threadIdx.x;   // 262144
    int co = tg >> 9, ci = tg & 511;
    const size_t spl = (size_t)9 * 512 * 512;
    for (int kk = 0; kk < 9; kk++) {
        float v = w[(size_t)(co * 512 + ci) * 9 + kk];
        ushort_t hi = f2bf(v);
        float r1 = v - bf2f(hi);
        ushort_t mid = f2bf(r1);
        float r2 = r1 - bf2f(mid);
        ushort_t lo = f2bf(r2);
        size_t base = ((size_t)kk * 512 + co) * 512 + ci;
        w3[base] = hi;
        w3[base + spl] = mid;
        w3[base + 2 * spl] = lo;
    }
}

// ---------------- K0: anchors + valid-position map ----------------
__global__ __launch_bounds__(1024) void k0_anchors(float* out, int* vpos,
                                                   const int* d_imgh, const int* d_imgw) {
    int tid = threadIdx.x;
    float imgh = (float)d_imgh[0], imgw = (float)d_imgw[0];
    __shared__ int cnt[1024];
    int base = tid * 36;
    int c = 0;
    for (int k = 0; k < 36; k++) {
        int a = base + k;
        int t = a % 9; int pix = a / 9; int x = pix & 63; int y = pix >> 6;
        float b0, b1, b2, b3; anchor_base(t, b0, b1, b2, b3);
        float a0 = b0 + 16.0f * y, a1 = b1 + 16.0f * x;
        float a2 = b2 + 16.0f * y, a3 = b3 + 16.0f * x;
        out[OUT_ANC + a * 4 + 0] = a0;
        out[OUT_ANC + a * 4 + 1] = a1;
        out[OUT_ANC + a * 4 + 2] = a2;
        out[OUT_ANC + a * 4 + 3] = a3;
        if (a0 >= 0.0f && a1 >= 0.0f && a2 <= imgh && a3 <= imgw) c++;
    }
    cnt[tid] = c;
    __syncthreads();
    for (int off = 1; off < 1024; off <<= 1) {
        int v = cnt[tid];
        int u = (tid >= off) ? cnt[tid - off] : 0;
        __syncthreads();
        cnt[tid] = v + u;
        __syncthreads();
    }
    int j = (tid == 0) ? 0 : cnt[tid - 1];
    for (int k = 0; k < 36; k++) {
        int a = base + k;
        int t = a % 9; int pix = a / 9; int x = pix & 63; int y = pix >> 6;
        float b0, b1, b2, b3; anchor_base(t, b0, b1, b2, b3);
        float a0 = b0 + 16.0f * y, a1 = b1 + 16.0f * x;
        float a2 = b2 + 16.0f * y, a3 = b3 + 16.0f * x;
        bool ok = (a0 >= 0.0f && a1 >= 0.0f && a2 <= imgh && a3 <= imgw);
        vpos[a] = ok ? j : -1;
        if (ok) j++;
    }
}

// ---------------- K1: 3x3 conv 512->512, bf16x3 MFMA, A in LDS, B reg-streamed ----------------
// 512 blocks, 256 threads. Tile: 64 px (1 y-row) x 128 co.
// nt = (bid>>1)&3 constant per bid%8 class -> each XCD's 3.5MB weight slice stays in its L2.
// B double-buffer parity: 9 taps/ct (odd) -> parity alternates per ct; PAR is a
// compile-time template value so breg indexing never becomes runtime (no scratch).
__global__ __launch_bounds__(256, 2) void k1_conv(const ushort_t* __restrict__ ft,
                                                  const ushort_t* __restrict__ w3,
                                                  const float* __restrict__ bias,
                                                  float* __restrict__ nhwc) {
    __shared__ ushort_t lds16[3 * A_SPL2];   // 47520 B -> 2 blocks/CU
    int tid = threadIdx.x;
    int bid = blockIdx.x;
    int nt = (bid >> 1) & 3;
    int mt = ((bid >> 3) << 1) | (bid & 1);  // 0..127 = b*64 + y
    int b = mt >> 6, y = mt & 63;
    int nb = nt << 7;

    int lane = tid & 63;
    int w = tid >> 6;                 // wave 0..3
    int wn = w << 5;                  // 32 co per wave
    int mlane = lane & 15;
    int quad = lane >> 4;
    int koff8 = quad * 8;

    const size_t FT_SPL = (size_t)2 * 64 * 64 * 512;
    const size_t W3_SPL = (size_t)9 * 512 * 512;

    int sx = tid >> 2;               // 0..63
    int sq = tid & 3;                // ci chunk of 8

    f32x4 acc[4][2];
#pragma unroll
    for (int mi = 0; mi < 4; mi++)
#pragma unroll
        for (int ni = 0; ni < 2; ni++) {
            acc[mi][ni][0] = 0.f; acc[mi][ni][1] = 0.f;
            acc[mi][ni][2] = 0.f; acc[mi][ni][3] = 0.f;
        }

    float bv[2];
#pragma unroll
    for (int ni = 0; ni < 2; ni++) bv[ni] = bias[nb + wn + ni * 16 + mlane];

    // zero x-halo columns xi=0,65 (all splits, all 3 rows) — written once, never overwritten
    if (tid < 72) {
        int s = tid / 24, rem = tid % 24;
        int r = rem >> 3, rem2 = rem & 7;
        int side = rem2 >> 2, q = rem2 & 3;
        uint4 z = make_uint4(0, 0, 0, 0);
        *(uint4*)&lds16[s * A_SPL2 + (r * 66 + side * 65) * 40 + q * 8] = z;
    }

    uint4 pbA[9];   // (r 0..2) x (s 0..2)
    auto loadA = [&](int ct) {
#pragma unroll
        for (int r = 0; r < 3; r++) {
            int yy = y - 1 + r;
            bool valid = (yy >= 0 && yy < 64);
            size_t rowbase = ((size_t)(b * 64 + (valid ? yy : 0)) * 64 + sx) * 512 + ct * 32 + sq * 8;
#pragma unroll
            for (int s = 0; s < 3; s++) {
                uint4 v = make_uint4(0, 0, 0, 0);
                if (valid) v = *(const uint4*)&ft[rowbase + (size_t)s * FT_SPL];
                pbA[r * 3 + s] = v;
            }
        }
    };
    auto writeA = [&]() {
#pragma unroll
        for (int r = 0; r < 3; r++)
#pragma unroll
            for (int s = 0; s < 3; s++)
                *(uint4*)&lds16[s * A_SPL2 + (r * 66 + sx + 1) * 40 + sq * 8] = pbA[r * 3 + s];
    };

    short8 breg[2][2][3];   // [buf][ni][split]
    auto loadB = [&](int buf, int tap, int ct) {
#pragma unroll
        for (int ni = 0; ni < 2; ni++) {
            size_t cobase = ((size_t)(tap * 512 + nb + wn + ni * 16 + mlane)) * 512 + ct * 32 + koff8;
#pragma unroll
            for (int s = 0; s < 3; s++)
                breg[buf][ni][s] = *(const short8*)&w3[(size_t)s * W3_SPL + cobase];
        }
    };

    auto ct_body = [&](int ct, auto par_c) {
        constexpr int PAR = decltype(par_c)::value;
        __syncthreads();     // previous ct's LDS reads complete
        writeA();
        __syncthreads();     // staging visible
        if (ct < 15) loadA(ct + 1);   // global->reg, hidden behind 9 taps of MFMA

#pragma unroll
        for (int tap = 0; tap < 9; tap++) {
            int cur = (tap + PAR) & 1, alt = cur ^ 1;   // compile-time after unroll
            if (tap < 8) loadB(alt, tap + 1, ct);
            else if (ct < 15) loadB(alt, 0, ct + 1);
            int ky = tap / 3, kx = tap - ky * 3;

            short8 af[3][4];
#pragma unroll
            for (int s = 0; s < 3; s++) {
                int ab = s * A_SPL2 + (ky * 66 + mlane + kx) * 40 + koff8;
#pragma unroll
                for (int mi = 0; mi < 4; mi++)
                    af[s][mi] = *(const short8*)&lds16[ab + mi * 640];
            }
#pragma unroll
            for (int t = 0; t < 6; t++) {
                const int sa_t[6] = {0, 0, 1, 0, 1, 2};
                const int sb_t[6] = {0, 1, 0, 2, 1, 0};
                int sa = sa_t[t], sb = sb_t[t];
#pragma unroll
                for (int mi = 0; mi < 4; mi++)
#pragma unroll
                    for (int ni = 0; ni < 2; ni++)
                        acc[mi][ni] = __builtin_amdgcn_mfma_f32_16x16x32_bf16(
                            af[sa][mi], breg[cur][ni][sb], acc[mi][ni], 0, 0, 0);
            }
        }
    };

    loadA(0);
    loadB(0, 0, 0);

    for (int ct = 0; ct < 16; ct += 2) {
        ct_body(ct, Ic<0>{});       // even ct: tap0 in buf0
        ct_body(ct + 1, Ic<1>{});   // odd ct: tap0 in buf1 (prefetched at prev tap8)
    }

    // epilogue: bias + relu, NHWC fp32
#pragma unroll
    for (int mi = 0; mi < 4; mi++) {
#pragma unroll
        for (int r = 0; r < 4; r++) {
            int x = mi * 16 + quad * 4 + r;
            size_t obase = ((size_t)(b * 64 + y) * 64 + x) * 512;
#pragma unroll
            for (int ni = 0; ni < 2; ni++) {
                int co = nb + wn + ni * 16 + mlane;
                float v = acc[mi][ni][r] + bv[ni];
                nhwc[obase + co] = fmaxf(v, 0.0f);
            }
        }
    }
}

// ---------------- K2: 1x1 heads + softmax + decode + score keys (NHWC input) ----------------
__global__ __launch_bounds__(256) void k2_heads(const float* __restrict__ nhwc,
                                                const float* __restrict__ cls_w,
                                                const float* __restrict__ cls_b,
                                                const float* __restrict__ reg_w,
                                                const float* __restrict__ reg_b,
                                                const int* __restrict__ vpos,
                                                float* __restrict__ out,
                                                float* __restrict__ boxes_ws,
                                                u32* __restrict__ keys_ws,
                                                const int* d_imgh, const int* d_imgw) {
    int row = blockIdx.x;           // b*64 + y
    int b = row >> 6, y = row & 63;
    int tid = threadIdx.x;
    __shared__ float Al[64 * 65];   // [p][ci], pad 65
    __shared__ float Wl[54 * 64];   // [o][ci]
    __shared__ float Ob[54 * 64];   // [o][p]
    int p = tid & 63, g = tid >> 6;
    int o0 = g * 14;
    int no = (g == 3) ? 12 : 14;
    float acc[14];
#pragma unroll
    for (int i = 0; i < 14; i++) acc[i] = 0.0f;
    for (int cib = 0; cib < 512; cib += 64) {
        for (int s = tid; s < 4096; s += 256) {
            int kk = s & 63, pp = s >> 6;
            Al[pp * 65 + kk] = nhwc[((size_t)(b * 64 + y) * 64 + pp) * 512 + cib + kk];
        }
        for (int s = tid; s < 54 * 64; s += 256) {
            int o = s >> 6, kk = s & 63;
            Wl[s] = (o < 18) ? cls_w[o * 512 + cib + kk] : reg_w[(o - 18) * 512 + cib + kk];
        }
        __syncthreads();
        for (int kk = 0; kk < 64; kk++) {
            float a = Al[p * 65 + kk];
#pragma unroll
            for (int oo = 0; oo < 14; oo++)
                if (oo < no) acc[oo] += a * Wl[(o0 + oo) * 64 + kk];
        }
        __syncthreads();
    }
#pragma unroll
    for (int oo = 0; oo < 14; oo++)
        if (oo < no) {
            int o = o0 + oo;
            float bvv = (o < 18) ? cls_b[o] : reg_b[o - 18];
            Ob[o * 64 + p] = acc[oo] + bvv;
        }
    __syncthreads();
    float imgh = (float)d_imgh[0], imgw = (float)d_imgw[0];
    for (int task = tid; task < 576; task += 256) {
        int ta = task >> 6, p2 = task & 63;
        int a_idx = (y * 64 + p2) * 9 + ta;
        int j = vpos[a_idx];
        if (j < 0) continue;
        float c0 = Ob[(2 * ta) * 64 + p2], c1 = Ob[(2 * ta + 1) * 64 + p2];
        float m = fmaxf(c0, c1);
        float e0 = expf(c0 - m), e1 = expf(c1 - m);
        float sden = e0 + e1;
        float p0v = e0 / sden, p1v = e1 / sden;
        out[OUT_CLS + (size_t)(b * KANC + j) * 2 + 0] = p0v;
        out[OUT_CLS + (size_t)(b * KANC + j) * 2 + 1] = p1v;
        float l0 = Ob[(18 + 4 * ta + 0) * 64 + p2];
        float l1 = Ob[(18 + 4 * ta + 1) * 64 + p2];
        float l2 = Ob[(18 + 4 * ta + 2) * 64 + p2];
        float l3 = Ob[(18 + 4 * ta + 3) * 64 + p2];
        out[OUT_REG + (size_t)(b * KANC + j) * 4 + 0] = l0;
        out[OUT_REG + (size_t)(b * KANC + j) * 4 + 1] = l1;
        out[OUT_REG + (size_t)(b * KANC + j) * 4 + 2] = l2;
        out[OUT_REG + (size_t)(b * KANC + j) * 4 + 3] = l3;
        float b0, b1, b2, b3; anchor_base(ta, b0, b1, b2, b3);
        float ay1 = b0 + 16.0f * y, ax1 = b1 + 16.0f * p2;
        float ay2 = b2 + 16.0f * y, ax2 = b3 + 16.0f * p2;
        float h = ay2 - ay1, wdt = ax2 - ax1;
        float cy = ay1 + 0.5f * h, cx = ax1 + 0.5f * wdt;
        float ncy = l0 * h + cy, ncx = l1 * wdt + cx;
        float nh = h * expf(l2), nw = wdt * expf(l3);
        float by1 = fminf(fmaxf(ncy - 0.5f * nh, 0.0f), imgh);
        float bx1 = fminf(fmaxf(ncx - 0.5f * nw, 0.0f), imgw);
        float by2 = fminf(fmaxf(ncy + 0.5f * nh, 0.0f), imgh);
        float bx2 = fminf(fmaxf(ncx + 0.5f * nw, 0.0f), imgw);
        boxes_ws[(size_t)(b * KANC + j) * 4 + 0] = by1;
        boxes_ws[(size_t)(b * KANC + j) * 4 + 1] = bx1;
        boxes_ws[(size_t)(b * KANC + j) * 4 + 2] = by2;
        boxes_ws[(size_t)(b * KANC + j) * 4 + 3] = bx2;
        float hs = by2 - by1, wsz = bx2 - bx1;
        u32 key = 0;
        if (hs >= 16.0f && wsz >= 16.0f) key = __float_as_uint(p1v) + 1u;
        keys_ws[b * KANC + j] = key;
    }
}

// ---------------- K3: exact top-2000 (3-level radix) + bitonic sort ----------------
__device__ __forceinline__ void suffix_scan(u32* suf, const u32* hist, int N, int tid) {
    for (int i = tid; i < N; i += 1024) suf[i] = hist[i];
    if (tid == 0) suf[N] = 0;
    __syncthreads();
    for (int off = 1; off < N; off <<= 1) {
        u32 add0 = 0, add1 = 0;
        int i0 = tid, i1 = tid + 1024;
        if (i0 < N) add0 = (i0 + off < N) ? suf[i0 + off] : 0;
        if (i1 < N) add1 = (i1 + off < N) ? suf[i1 + off] : 0;
        __syncthreads();
        if (i0 < N) suf[i0] += add0;
        if (i1 < N) suf[i1] += add1;
        __syncthreads();
    }
}

__global__ __launch_bounds__(1024) void k3_select(const u32* __restrict__ keys_ws,
                                                  const float* __restrict__ boxes_ws,
                                                  u32* __restrict__ topkey,
                                                  float* __restrict__ topbox) {
    int b = blockIdx.x, tid = threadIdx.x;
    const u32* keys = keys_ws + (size_t)b * KANC;
    __shared__ u32 hist[2048];
    __shared__ u32 suf[2049];
    __shared__ int Ps;
    __shared__ int cnt;
    __shared__ u64 sbuf[4096];

    for (int i = tid; i < 2048; i += 1024) hist[i] = 0;
    __syncthreads();
    for (int i = tid; i < KANC; i += 1024) atomicAdd(&hist[keys[i] >> 20], 1u);
    __syncthreads();
    suffix_scan(suf, hist, 2048, tid);
    if (tid == 0) Ps = 0;
    __syncthreads();
    for (int i = tid; i < 2048; i += 1024)
        if (suf[i] >= (u32)PRE && suf[i + 1] < (u32)PRE) Ps = i;
    __syncthreads();
    u32 P1 = (u32)Ps;
    u32 quota2 = (u32)PRE - suf[P1 + 1];
    __syncthreads();

    for (int i = tid; i < 1024; i += 1024) hist[i] = 0;
    __syncthreads();
    for (int i = tid; i < KANC; i += 1024) {
        u32 k = keys[i];
        if ((k >> 20) == P1) atomicAdd(&hist[(k >> 10) & 1023u], 1u);
    }
    __syncthreads();
    suffix_scan(suf, hist, 1024, tid);
    if (tid == 0) Ps = 0;
    __syncthreads();
    for (int i = tid; i < 1024; i += 1024)
        if (suf[i] >= quota2 && suf[i + 1] < quota2) Ps = i;
    __syncthreads();
    u32 P2 = (u32)Ps;
    u32 quota3 = quota2 - suf[P2 + 1];
    __syncthreads();

    u32 pref = (P1 << 10) | P2;
    for (int i = tid; i < 1024; i += 1024) hist[i] = 0;
    __syncthreads();
    for (int i = tid; i < KANC; i += 1024) {
        u32 k = keys[i];
        if ((k >> 10) == pref) atomicAdd(&hist[k & 1023u], 1u);
    }
    __syncthreads();
    suffix_scan(suf, hist, 1024, tid);
    if (tid == 0) Ps = 0;
    __syncthreads();
    for (int i = tid; i < 1024; i += 1024)
        if (suf[i] >= quota3 && suf[i + 1] < quota3) Ps = i;
    __syncthreads();
    u32 P3 = (u32)Ps;
    u32 T = (P1 << 20) | (P2 << 10) | P3;
    u32 Tm = (T < 1u) ? 1u : T;

    for (int i = tid; i < 4096; i += 1024) sbuf[i] = 0ull;
    if (tid == 0) cnt = 0;
    __syncthreads();
    for (int i = tid; i < KANC; i += 1024) {
        u32 k = keys[i];
        if (k >= Tm) {
            int pos = atomicAdd(&cnt, 1);
            if (pos < 4096)
                sbuf[pos] = ((u64)k << 32) | (u64)(0xFFFFFFFFu - (u32)i);
        }
    }
    __syncthreads();

    for (int k2 = 2; k2 <= 4096; k2 <<= 1) {
        for (int j2 = k2 >> 1; j2 > 0; j2 >>= 1) {
            for (int i = tid; i < 4096; i += 1024) {
                int ixj = i ^ j2;
                if (ixj > i) {
                    u64 va = sbuf[i], vb = sbuf[ixj];
                    bool descRegion = ((i & k2) == 0);
                    if (descRegion ? (va < vb) : (va > vb)) {
                        sbuf[i] = vb; sbuf[ixj] = va;
                    }
                }
            }
            __syncthreads();
        }
    }

    for (int i = tid; i < PREP; i += 1024) {
        u64 v = sbuf[i];
        u32 kk = (u32)(v >> 32);
        u32 j = 0xFFFFFFFFu - (u32)(v & 0xFFFFFFFFull);
        bool good = (i < PRE) && (kk != 0);
        topkey[b * PREP + i] = good ? kk : 0;
        float4 bx = make_float4(0.0f, 0.0f, 0.0f, 0.0f);
        if (good) bx = *(const float4*)&boxes_ws[(size_t)(b * KANC + j) * 4];
        *(float4*)&topbox[(size_t)(b * PREP + i) * 4] = bx;
    }
}

// ---------------- K4: NMS suppression bitmask ----------------
__global__ __launch_bounds__(64) void k4_mask(const float* __restrict__ topbox,
                                              u64* __restrict__ mask) {
    int jb = blockIdx.x, ib = blockIdx.y, b = blockIdx.z;
    int lane = threadIdx.x;
    float4 bi = *(const float4*)&topbox[(size_t)(b * PREP + ib * 64 + lane) * 4];
    float4 bj = *(const float4*)&topbox[(size_t)(b * PREP + jb * 64 + lane) * 4];
    float ai = (bi.z - bi.x) * (bi.w - bi.y);
    float aj = (bj.z - bj.x) * (bj.w - bj.y);
    u64 word = 0;
    for (int ii = 0; ii < 64; ii++) {
        float y1 = __shfl(bi.x, ii), x1 = __shfl(bi.y, ii);
        float y2 = __shfl(bi.z, ii), x2 = __shfl(bi.w, ii);
        float aii = __shfl(ai, ii);
        float yy1 = fmaxf(y1, bj.x), xx1 = fmaxf(x1, bj.y);
        float yy2 = fminf(y2, bj.z), xx2 = fminf(x2, bj.w);
        float inter = fmaxf(yy2 - yy1, 0.0f) * fmaxf(xx2 - xx1, 0.0f);
        float iou = inter / (aii + aj - inter + 1e-9f);
        u64 bal = __ballot(iou > 0.7f);
        if (lane == ii) word = bal;
    }
    mask[(size_t)(b * PREP + ib * 64 + lane) * 32 + jb] = word;
}

// ---------------- K5: sequential greedy scan + roi output ----------------
__global__ __launch_bounds__(64) void k5_nms(const u32* __restrict__ topkey,
                                             const float* __restrict__ topbox,
                                             const u64* __restrict__ mask,
                                             float* __restrict__ out) {
    int b = blockIdx.x;
    int lane = threadIdx.x;
    __shared__ u32 keys_s[PREP];
    __shared__ int kept[POST];
    for (int s = lane; s < PREP; s += 64) keys_s[s] = topkey[b * PREP + s];
    __syncthreads();
    const u64* mb = mask + (size_t)b * PREP * 32;
    u64 remv = 0;
    const int CH = 16;
    u64 bufA[CH], bufB[CH];
    auto loadRows = [&](u64* buf, int base) {
#pragma unroll
        for (int k = 0; k < CH; k++)
            buf[k] = (lane < 32) ? mb[(size_t)(base + k) * 32 + lane] : 0ull;
    };
    int nk = 0;
    bool done = false;
    loadRows(bufA, 0);
    for (int base = 0; base < PRE && !done; base += 2 * CH) {
        loadRows(bufB, base + CH);
#pragma unroll
        for (int k = 0; k < CH; k++) {
            int i = base + k;
            u64 wv = __shfl(remv, i >> 6);
            if (!((wv >> (i & 63)) & 1ull) && keys_s[i] != 0) {
                remv |= bufA[k];
                if (lane == 0) kept[nk] = i;
                nk++;
                if (nk == POST) { done = true; break; }
            }
        }
        if (!done && base + CH < PRE) {
            if (base + 2 * CH < PRE) loadRows(bufA, base + 2 * CH);
#pragma unroll
            for (int k = 0; k < CH; k++) {
                int i = base + CH + k;
                u64 wv = __shfl(remv, i >> 6);
                if (!((wv >> (i & 63)) & 1ull) && keys_s[i] != 0) {
                    remv |= bufB[k];
                    if (lane == 0) kept[nk] = i;
                    nk++;
                    if (nk == POST) { done = true; break; }
                }
            }
        }
    }
    __syncthreads();
    for (int s = lane; s < POST; s += 64) {
        float4 bx = make_float4(0.0f, 0.0f, 0.0f, 0.0f);
        if (s < nk) bx = *(const float4*)&topbox[(size_t)(b * PREP + kept[s]) * 4];
        *(float4*)&out[OUT_ROI + (size_t)(b * POST + s) * 4] = bx;
        out[OUT_RID + b * POST + s] = (float)b;
    }
}

extern "C" void kernel_launch(void* const* d_in, const int* in_sizes, int n_in,
                              void* d_out, int out_size, void* d_ws, size_t ws_size,
                              hipStream_t stream) {
    (void)in_sizes; (void)n_in; (void)out_size; (void)ws_size;
    const float* feat    = (const float*)d_in[0];
    const float* share_w = (const float*)d_in[1];
    const float* share_b = (const float*)d_in[2];
    const float* cls_w   = (const float*)d_in[3];
    const float* cls_b   = (const float*)d_in[4];
    const float* reg_w   = (const float*)d_in[5];
    const float* reg_b   = (const float*)d_in[6];
    const int*   imgh    = (const int*)d_in[7];
    const int*   imgw    = (const int*)d_in[8];
    float* out = (float*)d_out;
    char* ws = (char*)d_ws;
    float*     nhwc   = (float*)(ws + WS_NHWC);
    ushort_t*  ft     = (ushort_t*)(ws + WS_FT);
    ushort_t*  w3     = (ushort_t*)(ws + WS_W3);
    int*       vpos   = (int*)(ws + WS_VPOS);
    float*     boxes  = (float*)(ws + WS_BOXES);
    u32*       keys   = (u32*)(ws + WS_KEYS);
    float*     topbox = (float*)(ws + WS_TOPBOX);
    u32*       topkey = (u32*)(ws + WS_TOPKEY);
    u64*       mask   = (u64*)(ws + WS_MASK);

    t1_feat<<<dim3(8, 128), 256, 0, stream>>>(feat, ft);
    t2_wgt<<<1024, 256, 0, stream>>>(share_w, w3);
    k0_anchors<<<1, 1024, 0, stream>>>(out, vpos, imgh, imgw);
    k1_conv<<<512, 256, 0, stream>>>(ft, w3, share_b, nhwc);
    k2_heads<<<128, 256, 0, stream>>>(nhwc, cls_w, cls_b, reg_w, reg_b, vpos,
                                      out, boxes, keys, imgh, imgw);
    k3_select<<<2, 1024, 0, stream>>>(keys, boxes, topkey, topbox);
    k4_mask<<<dim3(32, 32, 2), 64, 0, stream>>>(topbox, mask);
    k5_nms<<<2, 64, 0, stream>>>(topkey, topbox, mask, out);
}

// Round 5
// 663.421 us; speedup vs baseline: 2.2561x; 1.0940x over previous
//
#include <hip/hip_runtime.h>
#include <math.h>

typedef unsigned int u32;
typedef unsigned long long u64;
typedef unsigned short ushort_t;

typedef __attribute__((ext_vector_type(8))) short short8;
typedef __attribute__((ext_vector_type(16))) float f32x16;

#define KANC 18376
#define PRE 2000
#define PREP 2048
#define POST 300

#define OUT_CLS 0
#define OUT_REG 73504
#define OUT_ROI 220512
#define OUT_RID 222912
#define OUT_ANC 223512

// ws byte offsets (unchanged from R4; no new buffers)
#define WS_NHWC   0u
#define WS_FT     16777216u
#define WS_W3     41943040u
#define WS_VPOS   56098816u
#define WS_BOXES  56246272u
#define WS_KEYS   56834304u
#define WS_TOPBOX 56981312u
#define WS_TOPKEY 57046848u
#define WS_MASK   57063232u

// k1 LDS: A only, 3 splits x 3 rows x 66 xi x (32ci pad to 40)
#define A_SPL2 7920   // ushorts per split (3*66*40)

__device__ __forceinline__ ushort_t f2bf(float f) {
    u32 u = __float_as_uint(f);
    u32 r = (u + 0x7FFFu + ((u >> 16) & 1u)) >> 16;
    return (ushort_t)r;
}
__device__ __forceinline__ float bf2f(ushort_t h) {
    return __uint_as_float(((u32)h) << 16);
}

// hardcoded correctly-rounded doubles: sqrt(0.5), 1, sqrt(2)
__device__ __forceinline__ void anchor_base(int t, float& y1, float& x1, float& y2, float& x2) {
    const double SQ[3] = {0.7071067811865476, 1.0, 1.4142135623730951};
    const double SC[3] = {8.0, 16.0, 32.0};
    int ri = t / 3, si = t % 3;
    double h = 16.0 * SC[si] * SQ[ri];        // exact pow2 * correctly-rounded sqrt == numpy
    double w = 16.0 * SC[si] * SQ[2 - ri];
    y1 = (float)(8.0 - h * 0.5);
    x1 = (float)(8.0 - w * 0.5);
    y2 = (float)(8.0 + h * 0.5);
    x2 = (float)(8.0 + w * 0.5);
}

// ---------------- T1: feat NCHW fp32 -> ft[s][b][y][x][ci] bf16x3 ----------------
__global__ __launch_bounds__(256) void t1_feat(const float* __restrict__ feat,
                                               ushort_t* __restrict__ ft) {
    int by = blockIdx.y;            // b*64 + y
    int b = by >> 6, y = by & 63;
    int ci0 = blockIdx.x * 64;
    int tid = threadIdx.x;
    __shared__ float tile[64 * 65];
    for (int it = 0; it < 16; it++) {
        int idx = it * 256 + tid;
        int ci = idx >> 6, x = idx & 63;
        tile[ci * 65 + x] = feat[((size_t)(b * 512 + ci0 + ci) * 64 + y) * 64 + x];
    }
    __syncthreads();
    for (int it = 0; it < 16; it++) {
        int idx = it * 256 + tid;
        int x = idx >> 6, ci = idx & 63;
        float v = tile[ci * 65 + x];
        ushort_t hi = f2bf(v);
        float r1 = v - bf2f(hi);
        ushort_t mid = f2bf(r1);
        float r2 = r1 - bf2f(mid);
        ushort_t lo = f2bf(r2);
        size_t base = ((size_t)(b * 64 + y) * 64 + x) * 512 + ci0 + ci;
        const size_t spl = (size_t)2 * 64 * 64 * 512;
        ft[base] = hi;
        ft[base + spl] = mid;
        ft[base + 2 * spl] = lo;
    }
}

// ---------------- T2: weights OIHW fp32 -> w3[s][kykx][co][ci] bf16x3 ----------------
__global__ __launch_bounds__(256) void t2_wgt(const float* __restrict__ w,
                                              ushort_t* __restrict__ w3) {
    int tg = blockIdx.x * 256 + threadIdx.x;   // 262144
    int co = tg >> 9, ci = tg & 511;
    const size_t spl = (size_t)9 * 512 * 512;
    for (int kk = 0; kk < 9; kk++) {
        float v = w[(size_t)(co * 512 + ci) * 9 + kk];
        ushort_t hi = f2bf(v);
        float r1 = v - bf2f(hi);
        ushort_t mid = f2bf(r1);
        float r2 = r1 - bf2f(mid);
        ushort_t lo = f2bf(r2);
        size_t base = ((size_t)kk * 512 + co) * 512 + ci;
        w3[base] = hi;
        w3[base + spl] = mid;
        w3[base + 2 * spl] = lo;
    }
}

// ---------------- K0: anchors + valid-position map, fully parallel closed form ----------------
// ordering: a = (y*64+x)*9 + t. j(a) = sum_t' [rows_before(t',y)*W(t') + cols_before(t',y,x)]
//           + #{t'<t valid at (y,x)}. Validity is a per-type rectangle; margins >= 2.0 from
//           all boundaries so int bounds match the reference's f32 comparisons exactly.
__global__ __launch_bounds__(256) void k0_anchors(float* out, int* vpos,
                                                  const int* d_imgh, const int* d_imgw) {
    int a = blockIdx.x * 256 + threadIdx.x;   // 36864
    float imgh = (float)d_imgh[0], imgw = (float)d_imgw[0];
    int t = a % 9, pix = a / 9, x = pix & 63, y = pix >> 6;
    int j = 0;
    bool myvalid = false;
#pragma unroll
    for (int tt = 0; tt < 9; tt++) {
        float c0, c1, c2, c3;
        anchor_base(tt, c0, c1, c2, c3);
        int ylo = (int)((-c0) / 16.0f) + 1;         // c0 < 0 for all 9 types
        int yhi = (int)((imgh - c2) / 16.0f);
        int xlo = (int)((-c1) / 16.0f) + 1;
        int xhi = (int)((imgw - c3) / 16.0f);
        ylo = max(ylo, 0); yhi = min(yhi, 63);
        xlo = max(xlo, 0); xhi = min(xhi, 63);
        int Wt  = max(xhi - xlo + 1, 0);
        int nry = max(yhi - ylo + 1, 0);
        int rb  = min(max(y - ylo, 0), nry);
        bool vy = (y >= ylo) && (y <= yhi);
        int cb  = vy ? min(max(x - xlo, 0), Wt) : 0;
        bool val = vy && (x >= xlo) && (x <= xhi);
        j += rb * Wt + cb + ((tt < t && val) ? 1 : 0);
        if (tt == t) {
            myvalid = val;
            float4 o;
            o.x = c0 + 16.0f * y;
            o.y = c1 + 16.0f * x;
            o.z = c2 + 16.0f * y;
            o.w = c3 + 16.0f * x;
            *(float4*)&out[OUT_ANC + a * 4] = o;
        }
    }
    vpos[a] = myvalid ? j : -1;
}

// ---------------- K1: 3x3 conv 512->512, bf16x3, 32x32x16 MFMA, split-K(2) ----------------
// Grid 1024 = 128 mt x 4 nt x 2 kh; bid&7 = (nt<<1)|mt_lsb -> nt constant per XCD class
// (3.54 MB weight slice resident in its 4 MB L2; both kh halves on same XCD).
// 3 blocks/CU (LDS 47.5KB), 12 waves/CU. Partial sums atomicAdd'ed into zeroed nhwc
// (2-operand fp32 add: order-independent). 18 (tap,kstep) units per ct -> even count,
// register B double-buffer parity stable across ct.
__global__ __launch_bounds__(256, 3) void k1_conv(const ushort_t* __restrict__ ft,
                                                  const ushort_t* __restrict__ w3,
                                                  float* __restrict__ nhwc) {
    __shared__ ushort_t lds16[3 * A_SPL2];   // 47520 B
    int tid = threadIdx.x;
    int bid = blockIdx.x;
    int nt = (bid >> 1) & 3;
    int kh = (bid >> 3) & 1;
    int mt = ((bid >> 4) << 1) | (bid & 1);  // 0..127 = b*64 + y
    int b = mt >> 6, y = mt & 63;
    int nb = nt << 7;
    int ct0 = kh * 8;

    int lane = tid & 63;
    int w = tid >> 6;                 // wave 0..3
    int wn = w << 5;                  // 32 co per wave
    int nlane = lane & 31;            // m (x) / n (co) lane
    int kgrp8 = (lane >> 5) * 8;      // k-group offset (ushorts)

    const size_t FT_SPL = (size_t)2 * 64 * 64 * 512;
    const size_t W3_SPL = (size_t)9 * 512 * 512;

    int sx = tid >> 2;               // 0..63
    int sq = tid & 3;                // ci chunk of 8

    f32x16 acc[2];
#pragma unroll
    for (int mi = 0; mi < 2; mi++)
#pragma unroll
        for (int r = 0; r < 16; r++) acc[mi][r] = 0.0f;

    // zero x-halo columns xi=0,65 (all splits, all 3 rows) — written once
    if (tid < 72) {
        int s = tid / 24, rem = tid % 24;
        int r = rem >> 3, rem2 = rem & 7;
        int side = rem2 >> 2, q = rem2 & 3;
        uint4 z = make_uint4(0, 0, 0, 0);
        *(uint4*)&lds16[s * A_SPL2 + (r * 66 + side * 65) * 40 + q * 8] = z;
    }

    uint4 pbA[9];   // (r 0..2) x (s 0..2)
    auto loadA = [&](int ct) {
#pragma unroll
        for (int r = 0; r < 3; r++) {
            int yy = y - 1 + r;
            bool valid = (yy >= 0 && yy < 64);
            size_t rowbase = ((size_t)(b * 64 + (valid ? yy : 0)) * 64 + sx) * 512 + ct * 32 + sq * 8;
#pragma unroll
            for (int s = 0; s < 3; s++) {
                uint4 v = make_uint4(0, 0, 0, 0);
                if (valid) v = *(const uint4*)&ft[rowbase + (size_t)s * FT_SPL];
                pbA[r * 3 + s] = v;
            }
        }
    };
    auto writeA = [&]() {
#pragma unroll
        for (int r = 0; r < 3; r++)
#pragma unroll
            for (int s = 0; s < 3; s++)
                *(uint4*)&lds16[s * A_SPL2 + (r * 66 + sx + 1) * 40 + sq * 8] = pbA[r * 3 + s];
    };

    short8 breg[2][3];   // [buf][split]
    auto loadB = [&](int buf, int tap, int ks, int ct) {
        size_t cobase = ((size_t)(tap * 512 + nb + wn + nlane)) * 512 + ct * 32 + ks * 16 + kgrp8;
#pragma unroll
        for (int s = 0; s < 3; s++)
            breg[buf][s] = *(const short8*)&w3[(size_t)s * W3_SPL + cobase];
    };

    loadA(ct0);
    loadB(0, 0, 0, ct0);

    for (int ct = ct0; ct < ct0 + 8; ct++) {
        __syncthreads();     // previous ct's LDS reads complete
        writeA();
        __syncthreads();     // staging visible
        if (ct + 1 < ct0 + 8) loadA(ct + 1);

#pragma unroll
        for (int u = 0; u < 18; u++) {
            int cur = u & 1, alt = cur ^ 1;   // compile-time after unroll
            if (u + 1 < 18) loadB(alt, (u + 1) >> 1, (u + 1) & 1, ct);
            else if (ct + 1 < ct0 + 8) loadB(alt, 0, 0, ct + 1);
            int tap = u >> 1, ks = u & 1;
            int ky = tap / 3, kx = tap - ky * 3;

            short8 af[3][2];
#pragma unroll
            for (int s = 0; s < 3; s++) {
#pragma unroll
                for (int mi = 0; mi < 2; mi++)
                    af[s][mi] = *(const short8*)&lds16[s * A_SPL2 +
                        (ky * 66 + mi * 32 + nlane + kx) * 40 + ks * 16 + kgrp8];
            }
#pragma unroll
            for (int t = 0; t < 6; t++) {
                const int sa_t[6] = {0, 0, 1, 0, 1, 2};
                const int sb_t[6] = {0, 1, 0, 2, 1, 0};
                int sa = sa_t[t], sb = sb_t[t];
#pragma unroll
                for (int mi = 0; mi < 2; mi++)
                    acc[mi] = __builtin_amdgcn_mfma_f32_32x32x16_bf16(
                        af[sa][mi], breg[cur][sb], acc[mi], 0, 0, 0);
            }
        }
    }

    // epilogue: atomic partial-sum accumulate (no bias/relu here; k2 applies them)
    int co = nb + wn + nlane;
#pragma unroll
    for (int mi = 0; mi < 2; mi++) {
#pragma unroll
        for (int r = 0; r < 16; r++) {
            int xx = mi * 32 + (r & 3) + 8 * (r >> 2) + 4 * (lane >> 5);
            atomicAdd(&nhwc[((size_t)(b * 64 + y) * 64 + xx) * 512 + co], acc[mi][r]);
        }
    }
}

// ---------------- K2: 1x1 heads + softmax + decode + score keys ----------------
// nhwc holds raw conv sums; apply share_b + relu at load. float4 LDS reads (pad 68).
__global__ __launch_bounds__(256) void k2_heads(const float* __restrict__ nhwc,
                                                const float* __restrict__ share_b,
                                                const float* __restrict__ cls_w,
                                                const float* __restrict__ cls_b,
                                                const float* __restrict__ reg_w,
                                                const float* __restrict__ reg_b,
                                                const int* __restrict__ vpos,
                                                float* __restrict__ out,
                                                float* __restrict__ boxes_ws,
                                                u32* __restrict__ keys_ws,
                                                const int* d_imgh, const int* d_imgw) {
    int row = blockIdx.x;           // b*64 + y
    int b = row >> 6, y = row & 63;
    int tid = threadIdx.x;
    __shared__ float Al[64 * 68];   // [p][ci], pad 68 (16B-aligned rows)
    __shared__ float Wl[54 * 64];   // [o][ci]
    __shared__ float Ob[54 * 64];   // [o][p]
    int p = tid & 63, g = tid >> 6;
    int o0 = g * 14;
    int no = (g == 3) ? 12 : 14;
    float acc[14];
#pragma unroll
    for (int i = 0; i < 14; i++) acc[i] = 0.0f;
    for (int cib = 0; cib < 512; cib += 64) {
        for (int s = tid; s < 4096; s += 256) {
            int kk = s & 63, pp = s >> 6;
            float v = nhwc[((size_t)(b * 64 + y) * 64 + pp) * 512 + cib + kk] + share_b[cib + kk];
            Al[pp * 68 + kk] = fmaxf(v, 0.0f);
        }
        for (int s = tid; s < 54 * 64; s += 256) {
            int o = s >> 6, kk = s & 63;
            Wl[s] = (o < 18) ? cls_w[o * 512 + cib + kk] : reg_w[(o - 18) * 512 + cib + kk];
        }
        __syncthreads();
        for (int kq = 0; kq < 16; kq++) {
            float4 a4 = *(const float4*)&Al[p * 68 + kq * 4];
#pragma unroll
            for (int oo = 0; oo < 14; oo++)
                if (oo < no) {
                    float4 w4 = *(const float4*)&Wl[(o0 + oo) * 64 + kq * 4];
                    acc[oo] += a4.x * w4.x + a4.y * w4.y + a4.z * w4.z + a4.w * w4.w;
                }
        }
        __syncthreads();
    }
#pragma unroll
    for (int oo = 0; oo < 14; oo++)
        if (oo < no) {
            int o = o0 + oo;
            float bvv = (o < 18) ? cls_b[o] : reg_b[o - 18];
            Ob[o * 64 + p] = acc[oo] + bvv;
        }
    __syncthreads();
    float imgh = (float)d_imgh[0], imgw = (float)d_imgw[0];
    for (int task = tid; task < 576; task += 256) {
        int ta = task >> 6, p2 = task & 63;
        int a_idx = (y * 64 + p2) * 9 + ta;
        int j = vpos[a_idx];
        if (j < 0) continue;
        float c0 = Ob[(2 * ta) * 64 + p2], c1 = Ob[(2 * ta + 1) * 64 + p2];
        float m = fmaxf(c0, c1);
        float e0 = expf(c0 - m), e1 = expf(c1 - m);
        float sden = e0 + e1;
        float p0v = e0 / sden, p1v = e1 / sden;
        out[OUT_CLS + (size_t)(b * KANC + j) * 2 + 0] = p0v;
        out[OUT_CLS + (size_t)(b * KANC + j) * 2 + 1] = p1v;
        float l0 = Ob[(18 + 4 * ta + 0) * 64 + p2];
        float l1 = Ob[(18 + 4 * ta + 1) * 64 + p2];
        float l2 = Ob[(18 + 4 * ta + 2) * 64 + p2];
        float l3 = Ob[(18 + 4 * ta + 3) * 64 + p2];
        out[OUT_REG + (size_t)(b * KANC + j) * 4 + 0] = l0;
        out[OUT_REG + (size_t)(b * KANC + j) * 4 + 1] = l1;
        out[OUT_REG + (size_t)(b * KANC + j) * 4 + 2] = l2;
        out[OUT_REG + (size_t)(b * KANC + j) * 4 + 3] = l3;
        float b0, b1, b2, b3; anchor_base(ta, b0, b1, b2, b3);
        float ay1 = b0 + 16.0f * y, ax1 = b1 + 16.0f * p2;
        float ay2 = b2 + 16.0f * y, ax2 = b3 + 16.0f * p2;
        float h = ay2 - ay1, wdt = ax2 - ax1;
        float cy = ay1 + 0.5f * h, cx = ax1 + 0.5f * wdt;
        float ncy = l0 * h + cy, ncx = l1 * wdt + cx;
        float nh = h * expf(l2), nw = wdt * expf(l3);
        float by1 = fminf(fmaxf(ncy - 0.5f * nh, 0.0f), imgh);
        float bx1 = fminf(fmaxf(ncx - 0.5f * nw, 0.0f), imgw);
        float by2 = fminf(fmaxf(ncy + 0.5f * nh, 0.0f), imgh);
        float bx2 = fminf(fmaxf(ncx + 0.5f * nw, 0.0f), imgw);
        boxes_ws[(size_t)(b * KANC + j) * 4 + 0] = by1;
        boxes_ws[(size_t)(b * KANC + j) * 4 + 1] = bx1;
        boxes_ws[(size_t)(b * KANC + j) * 4 + 2] = by2;
        boxes_ws[(size_t)(b * KANC + j) * 4 + 3] = bx2;
        float hs = by2 - by1, wsz = bx2 - bx1;
        u32 key = 0;
        if (hs >= 16.0f && wsz >= 16.0f) key = __float_as_uint(p1v) + 1u;
        keys_ws[b * KANC + j] = key;
    }
}

// ---------------- K3: exact top-2000 (3-level radix) + bitonic sort ----------------
__device__ __forceinline__ void suffix_scan(u32* suf, const u32* hist, int N, int tid) {
    for (int i = tid; i < N; i += 1024) suf[i] = hist[i];
    if (tid == 0) suf[N] = 0;
    __syncthreads();
    for (int off = 1; off < N; off <<= 1) {
        u32 add0 = 0, add1 = 0;
        int i0 = tid, i1 = tid + 1024;
        if (i0 < N) add0 = (i0 + off < N) ? suf[i0 + off] : 0;
        if (i1 < N) add1 = (i1 + off < N) ? suf[i1 + off] : 0;
        __syncthreads();
        if (i0 < N) suf[i0] += add0;
        if (i1 < N) suf[i1] += add1;
        __syncthreads();
    }
}

__global__ __launch_bounds__(1024) void k3_select(const u32* __restrict__ keys_ws,
                                                  const float* __restrict__ boxes_ws,
                                                  u32* __restrict__ topkey,
                                                  float* __restrict__ topbox) {
    int b = blockIdx.x, tid = threadIdx.x;
    const u32* keys = keys_ws + (size_t)b * KANC;
    __shared__ u32 hist[2048];
    __shared__ u32 suf[2049];
    __shared__ int Ps;
    __shared__ int cnt;
    __shared__ u64 sbuf[4096];

    for (int i = tid; i < 2048; i += 1024) hist[i] = 0;
    __syncthreads();
    for (int i = tid; i < KANC; i += 1024) atomicAdd(&hist[keys[i] >> 20], 1u);
    __syncthreads();
    suffix_scan(suf, hist, 2048, tid);
    if (tid == 0) Ps = 0;
    __syncthreads();
    for (int i = tid; i < 2048; i += 1024)
        if (suf[i] >= (u32)PRE && suf[i + 1] < (u32)PRE) Ps = i;
    __syncthreads();
    u32 P1 = (u32)Ps;
    u32 quota2 = (u32)PRE - suf[P1 + 1];
    __syncthreads();

    for (int i = tid; i < 1024; i += 1024) hist[i] = 0;
    __syncthreads();
    for (int i = tid; i < KANC; i += 1024) {
        u32 k = keys[i];
        if ((k >> 20) == P1) atomicAdd(&hist[(k >> 10) & 1023u], 1u);
    }
    __syncthreads();
    suffix_scan(suf, hist, 1024, tid);
    if (tid == 0) Ps = 0;
    __syncthreads();
    for (int i = tid; i < 1024; i += 1024)
        if (suf[i] >= quota2 && suf[i + 1] < quota2) Ps = i;
    __syncthreads();
    u32 P2 = (u32)Ps;
    u32 quota3 = quota2 - suf[P2 + 1];
    __syncthreads();

    u32 pref = (P1 << 10) | P2;
    for (int i = tid; i < 1024; i += 1024) hist[i] = 0;
    __syncthreads();
    for (int i = tid; i < KANC; i += 1024) {
        u32 k = keys[i];
        if ((k >> 10) == pref) atomicAdd(&hist[k & 1023u], 1u);
    }
    __syncthreads();
    suffix_scan(suf, hist, 1024, tid);
    if (tid == 0) Ps = 0;
    __syncthreads();
    for (int i = tid; i < 1024; i += 1024)
        if (suf[i] >= quota3 && suf[i + 1] < quota3) Ps = i;
    __syncthreads();
    u32 P3 = (u32)Ps;
    u32 T = (P1 << 20) | (P2 << 10) | P3;
    u32 Tm = (T < 1u) ? 1u : T;

    for (int i = tid; i < 4096; i += 1024) sbuf[i] = 0ull;
    if (tid == 0) cnt = 0;
    __syncthreads();
    for (int i = tid; i < KANC; i += 1024) {
        u32 k = keys[i];
        if (k >= Tm) {
            int pos = atomicAdd(&cnt, 1);
            if (pos < 4096)
                sbuf[pos] = ((u64)k << 32) | (u64)(0xFFFFFFFFu - (u32)i);
        }
    }
    __syncthreads();

    for (int k2 = 2; k2 <= 4096; k2 <<= 1) {
        for (int j2 = k2 >> 1; j2 > 0; j2 >>= 1) {
            for (int i = tid; i < 4096; i += 1024) {
                int ixj = i ^ j2;
                if (ixj > i) {
                    u64 va = sbuf[i], vb = sbuf[ixj];
                    bool descRegion = ((i & k2) == 0);
                    if (descRegion ? (va < vb) : (va > vb)) {
                        sbuf[i] = vb; sbuf[ixj] = va;
                    }
                }
            }
            __syncthreads();
        }
    }

    for (int i = tid; i < PREP; i += 1024) {
        u64 v = sbuf[i];
        u32 kk = (u32)(v >> 32);
        u32 j = 0xFFFFFFFFu - (u32)(v & 0xFFFFFFFFull);
        bool good = (i < PRE) && (kk != 0);
        topkey[b * PREP + i] = good ? kk : 0;
        float4 bx = make_float4(0.0f, 0.0f, 0.0f, 0.0f);
        if (good) bx = *(const float4*)&boxes_ws[(size_t)(b * KANC + j) * 4];
        *(float4*)&topbox[(size_t)(b * PREP + i) * 4] = bx;
    }
}

// ---------------- K4: NMS suppression bitmask ----------------
__global__ __launch_bounds__(64) void k4_mask(const float* __restrict__ topbox,
                                              u64* __restrict__ mask) {
    int jb = blockIdx.x, ib = blockIdx.y, b = blockIdx.z;
    int lane = threadIdx.x;
    float4 bi = *(const float4*)&topbox[(size_t)(b * PREP + ib * 64 + lane) * 4];
    float4 bj = *(const float4*)&topbox[(size_t)(b * PREP + jb * 64 + lane) * 4];
    float ai = (bi.z - bi.x) * (bi.w - bi.y);
    float aj = (bj.z - bj.x) * (bj.w - bj.y);
    u64 word = 0;
    for (int ii = 0; ii < 64; ii++) {
        float y1 = __shfl(bi.x, ii), x1 = __shfl(bi.y, ii);
        float y2 = __shfl(bi.z, ii), x2 = __shfl(bi.w, ii);
        float aii = __shfl(ai, ii);
        float yy1 = fmaxf(y1, bj.x), xx1 = fmaxf(x1, bj.y);
        float yy2 = fminf(y2, bj.z), xx2 = fminf(x2, bj.w);
        float inter = fmaxf(yy2 - yy1, 0.0f) * fmaxf(xx2 - xx1, 0.0f);
        float iou = inter / (aii + aj - inter + 1e-9f);
        u64 bal = __ballot(iou > 0.7f);
        if (lane == ii) word = bal;
    }
    mask[(size_t)(b * PREP + ib * 64 + lane) * 32 + jb] = word;
}

// ---------------- K5: greedy scan via per-word candidate bitmask + ctz ----------------
// remv distributed: lane L (<32) holds suppression word L. Suppressed candidates are
// skipped at zero cost; dependency chain only over kept candidates (~300).
__global__ __launch_bounds__(64) void k5_nms(const u32* __restrict__ topkey,
                                             const float* __restrict__ topbox,
                                             const u64* __restrict__ mask,
                                             float* __restrict__ out) {
    int b = blockIdx.x;
    int lane = threadIdx.x;
    __shared__ int kept[POST];

    // validity bitmask, distributed like remv
    u64 validw = 0;
    for (int it = 0; it < 32; it++) {
        u64 wv = __ballot(topkey[b * PREP + it * 64 + lane] != 0);
        if (lane == it) validw = wv;
    }

    const u64* mb = mask + (size_t)b * PREP * 32;
    u64 remv = 0;
    const int CH = 16;
    u64 bufA[CH], bufB[CH];
    auto loadRows = [&](u64* buf, int base) {
#pragma unroll
        for (int k = 0; k < CH; k++)
            buf[k] = (lane < 32) ? mb[(size_t)(base + k) * 32 + lane] : 0ull;
    };
    int nk = 0;
    auto process = [&](u64* buf, int base) {
        int wi = base >> 6, sh = base & 63;
        u64 supw = __shfl(remv, wi);
        u64 valw = __shfl(validw, wi);
        u32 cand = (u32)(((~supw & valw) >> sh) & 0xFFFFull);
        while (cand) {
            int k = __builtin_ctz(cand);
            cand &= cand - 1;
            int i = base + k;
            remv |= buf[k];
            u64 rw = __shfl(buf[k], wi);
            cand &= ~((u32)((rw >> sh) & 0xFFFFull));
            if (lane == 0) kept[nk] = i;
            nk++;
            if (nk == POST) break;
        }
    };

    loadRows(bufA, 0);
    for (int base = 0; base < PRE && nk < POST; base += 2 * CH) {
        loadRows(bufB, base + CH);
        process(bufA, base);
        if (nk < POST && base + CH < PRE) {
            if (base + 2 * CH < PRE) loadRows(bufA, base + 2 * CH);
            process(bufB, base + CH);
        }
    }
    __syncthreads();
    for (int s = lane; s < POST; s += 64) {
        float4 bx = make_float4(0.0f, 0.0f, 0.0f, 0.0f);
        if (s < nk) bx = *(const float4*)&topbox[(size_t)(b * PREP + kept[s]) * 4];
        *(float4*)&out[OUT_ROI + (size_t)(b * POST + s) * 4] = bx;
        out[OUT_RID + b * POST + s] = (float)b;
    }
}

extern "C" void kernel_launch(void* const* d_in, const int* in_sizes, int n_in,
                              void* d_out, int out_size, void* d_ws, size_t ws_size,
                              hipStream_t stream) {
    (void)in_sizes; (void)n_in; (void)out_size; (void)ws_size;
    const float* feat    = (const float*)d_in[0];
    const float* share_w = (const float*)d_in[1];
    const float* share_b = (const float*)d_in[2];
    const float* cls_w   = (const float*)d_in[3];
    const float* cls_b   = (const float*)d_in[4];
    const float* reg_w   = (const float*)d_in[5];
    const float* reg_b   = (const float*)d_in[6];
    const int*   imgh    = (const int*)d_in[7];
    const int*   imgw    = (const int*)d_in[8];
    float* out = (float*)d_out;
    char* ws = (char*)d_ws;
    float*     nhwc   = (float*)(ws + WS_NHWC);
    ushort_t*  ft     = (ushort_t*)(ws + WS_FT);
    ushort_t*  w3     = (ushort_t*)(ws + WS_W3);
    int*       vpos   = (int*)(ws + WS_VPOS);
    float*     boxes  = (float*)(ws + WS_BOXES);
    u32*       keys   = (u32*)(ws + WS_KEYS);
    float*     topbox = (float*)(ws + WS_TOPBOX);
    u32*       topkey = (u32*)(ws + WS_TOPKEY);
    u64*       maskp  = (u64*)(ws + WS_MASK);

    hipMemsetAsync(nhwc, 0, (size_t)2 * 64 * 64 * 512 * 4, stream);
    t1_feat<<<dim3(8, 128), 256, 0, stream>>>(feat, ft);
    t2_wgt<<<1024, 256, 0, stream>>>(share_w, w3);
    k0_anchors<<<144, 256, 0, stream>>>(out, vpos, imgh, imgw);
    k1_conv<<<1024, 256, 0, stream>>>(ft, w3, nhwc);
    k2_heads<<<128, 256, 0, stream>>>(nhwc, share_b, cls_w, cls_b, reg_w, reg_b, vpos,
                                      out, boxes, keys, imgh, imgw);
    k3_select<<<2, 1024, 0, stream>>>(keys, boxes, topkey, topbox);
    k4_mask<<<dim3(32, 32, 2), 64, 0, stream>>>(topbox, maskp);
    k5_nms<<<2, 64, 0, stream>>>(topkey, topbox, maskp, out);
}

// Round 6
// 645.577 us; speedup vs baseline: 2.3185x; 1.0276x over previous
//
#include <hip/hip_runtime.h>
#include <math.h>

typedef unsigned int u32;
typedef unsigned long long u64;
typedef unsigned short ushort_t;

typedef __attribute__((ext_vector_type(8))) short short8;
typedef __attribute__((ext_vector_type(16))) float f32x16;

#define KANC 18376
#define PRE 2000
#define PREP 2048
#define POST 300

#define OUT_CLS 0
#define OUT_REG 73504
#define OUT_ROI 220512
#define OUT_RID 222912
#define OUT_ANC 223512

// ws byte offsets
#define WS_NHWC   0u
#define WS_FT     16777216u
#define WS_W3     41943040u
#define WS_VPOS   56098816u
#define WS_BOXES  56246272u
#define WS_KEYS   56834304u
#define WS_TOPBOX 56981312u
#define WS_TOPKEY 57046848u
#define WS_MASK   57063232u

// k1 LDS: A only, 3 splits x 3 rows x 66 xi x (32ci pad to 40)
#define A_SPL2 7920   // ushorts per split (3*66*40)

__device__ __forceinline__ ushort_t f2bf(float f) {
    u32 u = __float_as_uint(f);
    u32 r = (u + 0x7FFFu + ((u >> 16) & 1u)) >> 16;
    return (ushort_t)r;
}
__device__ __forceinline__ float bf2f(ushort_t h) {
    return __uint_as_float(((u32)h) << 16);
}
__device__ __forceinline__ u32 pack3(float v0, float v1, ushort_t* m0, ushort_t* m1,
                                     ushort_t* l0, ushort_t* l1) {
    ushort_t h0 = f2bf(v0);
    float r = v0 - bf2f(h0);
    *m0 = f2bf(r);
    *l0 = f2bf(r - bf2f(*m0));
    ushort_t h1 = f2bf(v1);
    float r1 = v1 - bf2f(h1);
    *m1 = f2bf(r1);
    *l1 = f2bf(r1 - bf2f(*m1));
    return (u32)h0 | ((u32)h1 << 16);
}

// hardcoded correctly-rounded doubles: sqrt(0.5), 1, sqrt(2)
__device__ __forceinline__ void anchor_base(int t, float& y1, float& x1, float& y2, float& x2) {
    const double SQ[3] = {0.7071067811865476, 1.0, 1.4142135623730951};
    const double SC[3] = {8.0, 16.0, 32.0};
    int ri = t / 3, si = t % 3;
    double h = 16.0 * SC[si] * SQ[ri];
    double w = 16.0 * SC[si] * SQ[2 - ri];
    y1 = (float)(8.0 - h * 0.5);
    x1 = (float)(8.0 - w * 0.5);
    y2 = (float)(8.0 + h * 0.5);
    x2 = (float)(8.0 + w * 0.5);
}

// ---------------- T12: fused input transforms ----------------
// bid < 1024: feat NCHW fp32 -> ft[s][b][y][x][ci] bf16x3 (u32-packed stores)
// bid >= 1024: weights OIHW fp32 -> w3[s][kykx][co][ci] bf16x3 (LDS-staged transpose)
__global__ __launch_bounds__(256) void t12_pre(const float* __restrict__ feat,
                                               const float* __restrict__ w,
                                               ushort_t* __restrict__ ft,
                                               ushort_t* __restrict__ w3) {
    __shared__ float lds[8 * 577];   // max(t1 4160, t2 4616)
    int tid = threadIdx.x;
    int bid = blockIdx.x;
    if (bid < 1024) {
        int by = bid >> 3;            // b*64 + y
        int b = by >> 6, y = by & 63;
        int ci0 = (bid & 7) * 64;
        for (int it = 0; it < 16; it++) {
            int idx = it * 256 + tid;
            int ci = idx >> 6, x = idx & 63;
            lds[ci * 65 + x] = feat[((size_t)(b * 512 + ci0 + ci) * 64 + y) * 64 + x];
        }
        __syncthreads();
        const size_t spl = (size_t)2 * 64 * 64 * 512;
        u32* ft32 = (u32*)ft;
        for (int it = 0; it < 8; it++) {
            int idx = it * 256 + tid;
            int x = idx >> 5, cp = idx & 31;
            float v0 = lds[(2 * cp) * 65 + x];
            float v1 = lds[(2 * cp + 1) * 65 + x];
            ushort_t m0, m1, l0, l1;
            u32 hi = pack3(v0, v1, &m0, &m1, &l0, &l1);
            size_t base = ((size_t)(b * 64 + y) * 64 + x) * 512 + ci0 + 2 * cp;
            ft32[base >> 1] = hi;
            ft32[(base + spl) >> 1] = (u32)m0 | ((u32)m1 << 16);
            ft32[(base + 2 * spl) >> 1] = (u32)l0 | ((u32)l1 << 16);
        }
    } else {
        int b2 = bid - 1024;          // 512 blocks: 64 co-blocks x 8 ci-blocks
        int cob = b2 >> 3;            // *8 co
        int cib = (b2 & 7) * 64;
        // stage 8 co x 576 floats (64 ci x 9 kk), coalesced
        for (int s = tid; s < 4608; s += 256) {
            int co = s / 576, r = s - co * 576;
            lds[co * 577 + r] = w[((size_t)(cob * 8 + co) * 512 + cib) * 9 + r];
        }
        __syncthreads();
        const size_t spl = (size_t)9 * 512 * 512;
        u32* w32 = (u32*)w3;
        int co = tid >> 5, cp = tid & 31;   // thread: 1 co x 2 ci
        for (int kk = 0; kk < 9; kk++) {
            float v0 = lds[co * 577 + (2 * cp) * 9 + kk];
            float v1 = lds[co * 577 + (2 * cp + 1) * 9 + kk];
            ushort_t m0, m1, l0, l1;
            u32 hi = pack3(v0, v1, &m0, &m1, &l0, &l1);
            size_t base = ((size_t)kk * 512 + cob * 8 + co) * 512 + cib + 2 * cp;
            w32[base >> 1] = hi;
            w32[(base + spl) >> 1] = (u32)m0 | ((u32)m1 << 16);
            w32[(base + 2 * spl) >> 1] = (u32)l0 | ((u32)l1 << 16);
        }
    }
}

// ---------------- K1: 3x3 conv 512->512, bf16x3, 32x32x16 MFMA ----------------
// Grid 512 = 128 mt x 2 nt x 2 kh. bid%8 fixes (nt,kh,mt_lsb) -> per-XCD 3.54MB
// weight slice L2-resident. Wave covers 64 co (ni=2): 6 A-ds_reads feed 24 MFMAs
// (was 12) -> LDS pipe demand halves vs R5. Partial sums atomicAdd (fp32, 2-operand,
// order-independent) into zeroed nhwc; bias+relu in k2.
__global__ __launch_bounds__(256, 2) void k1_conv(const ushort_t* __restrict__ ft,
                                                  const ushort_t* __restrict__ w3,
                                                  float* __restrict__ nhwc) {
    __shared__ ushort_t lds16[3 * A_SPL2];   // 47520 B
    int tid = threadIdx.x;
    int bid = blockIdx.x;
    int nt = (bid >> 1) & 1;
    int kh = (bid >> 2) & 1;
    int mt = ((bid >> 3) << 1) | (bid & 1);  // 0..127 = b*64 + y
    int b = mt >> 6, y = mt & 63;
    int nb = nt << 8;
    int ct0 = kh * 8;

    int lane = tid & 63;
    int w = tid >> 6;                 // wave 0..3
    int wn = w << 6;                  // 64 co per wave
    int nlane = lane & 31;
    int kgrp8 = (lane >> 5) * 8;

    const size_t FT_SPL = (size_t)2 * 64 * 64 * 512;
    const size_t W3_SPL = (size_t)9 * 512 * 512;

    int sx = tid >> 2;
    int sq = tid & 3;

    f32x16 acc[2][2];   // [mi][ni]
#pragma unroll
    for (int mi = 0; mi < 2; mi++)
#pragma unroll
        for (int ni = 0; ni < 2; ni++)
#pragma unroll
            for (int r = 0; r < 16; r++) acc[mi][ni][r] = 0.0f;

    // zero x-halo columns xi=0,65
    if (tid < 72) {
        int s = tid / 24, rem = tid % 24;
        int r = rem >> 3, rem2 = rem & 7;
        int side = rem2 >> 2, q = rem2 & 3;
        uint4 z = make_uint4(0, 0, 0, 0);
        *(uint4*)&lds16[s * A_SPL2 + (r * 66 + side * 65) * 40 + q * 8] = z;
    }

    uint4 pbA[9];
    auto loadA = [&](int ct) {
#pragma unroll
        for (int r = 0; r < 3; r++) {
            int yy = y - 1 + r;
            bool valid = (yy >= 0 && yy < 64);
            size_t rowbase = ((size_t)(b * 64 + (valid ? yy : 0)) * 64 + sx) * 512 + ct * 32 + sq * 8;
#pragma unroll
            for (int s = 0; s < 3; s++) {
                uint4 v = make_uint4(0, 0, 0, 0);
                if (valid) v = *(const uint4*)&ft[rowbase + (size_t)s * FT_SPL];
                pbA[r * 3 + s] = v;
            }
        }
    };
    auto writeA = [&]() {
#pragma unroll
        for (int r = 0; r < 3; r++)
#pragma unroll
            for (int s = 0; s < 3; s++)
                *(uint4*)&lds16[s * A_SPL2 + (r * 66 + sx + 1) * 40 + sq * 8] = pbA[r * 3 + s];
    };

    short8 breg[2][2][3];   // [buf][ni][split]
    auto loadB = [&](int buf, int tap, int ks, int ct) {
#pragma unroll
        for (int ni = 0; ni < 2; ni++) {
            size_t cobase = ((size_t)(tap * 512 + nb + wn + ni * 32 + nlane)) * 512
                            + ct * 32 + ks * 16 + kgrp8;
#pragma unroll
            for (int s = 0; s < 3; s++)
                breg[buf][ni][s] = *(const short8*)&w3[(size_t)s * W3_SPL + cobase];
        }
    };

    loadA(ct0);
    loadB(0, 0, 0, ct0);

    for (int ct = ct0; ct < ct0 + 8; ct++) {
        __syncthreads();
        writeA();
        __syncthreads();
        if (ct + 1 < ct0 + 8) loadA(ct + 1);

#pragma unroll
        for (int u = 0; u < 18; u++) {
            int cur = u & 1, alt = cur ^ 1;   // compile-time after unroll; 18 even -> parity stable
            if (u + 1 < 18) loadB(alt, (u + 1) >> 1, (u + 1) & 1, ct);
            else if (ct + 1 < ct0 + 8) loadB(alt, 0, 0, ct + 1);
            int tap = u >> 1, ks = u & 1;
            int ky = tap / 3, kx = tap - ky * 3;

            short8 af[3][2];
#pragma unroll
            for (int s = 0; s < 3; s++) {
#pragma unroll
                for (int mi = 0; mi < 2; mi++)
                    af[s][mi] = *(const short8*)&lds16[s * A_SPL2 +
                        (ky * 66 + mi * 32 + nlane + kx) * 40 + ks * 16 + kgrp8];
            }
#pragma unroll
            for (int t = 0; t < 6; t++) {
                const int sa_t[6] = {0, 0, 1, 0, 1, 2};
                const int sb_t[6] = {0, 1, 0, 2, 1, 0};
                int sa = sa_t[t], sb = sb_t[t];
#pragma unroll
                for (int mi = 0; mi < 2; mi++)
#pragma unroll
                    for (int ni = 0; ni < 2; ni++)
                        acc[mi][ni] = __builtin_amdgcn_mfma_f32_32x32x16_bf16(
                            af[sa][mi], breg[cur][ni][sb], acc[mi][ni], 0, 0, 0);
            }
        }
    }

    // epilogue: atomic partial-sum accumulate
#pragma unroll
    for (int mi = 0; mi < 2; mi++) {
#pragma unroll
        for (int ni = 0; ni < 2; ni++) {
            int co = nb + wn + ni * 32 + nlane;
#pragma unroll
            for (int r = 0; r < 16; r++) {
                int xx = mi * 32 + (r & 3) + 8 * (r >> 2) + 4 * (lane >> 5);
                atomicAdd(&nhwc[((size_t)(b * 64 + y) * 64 + xx) * 512 + co], acc[mi][ni][r]);
            }
        }
    }
}

// ---------------- K2: heads + softmax + decode + keys + anchors/vpos (k0 fused) ----------------
// 256 blocks = (b*64+y) x 2 px-halves. Thread tile 2p x 4o (o padded to 64):
// 96 LDS b128/thread/cib vs 240 in the broadcast layout.
__global__ __launch_bounds__(256) void k2_heads(const float* __restrict__ nhwc,
                                                const float* __restrict__ share_b,
                                                const float* __restrict__ cls_w,
                                                const float* __restrict__ cls_b,
                                                const float* __restrict__ reg_w,
                                                const float* __restrict__ reg_b,
                                                float* __restrict__ out,
                                                float* __restrict__ boxes_ws,
                                                u32* __restrict__ keys_ws,
                                                const int* d_imgh, const int* d_imgw) {
    int bid = blockIdx.x;
    int row = bid >> 1;             // b*64 + y
    int b = row >> 6, y = row & 63;
    int h = bid & 1;                // px half
    int p0 = h * 32;
    int tid = threadIdx.x;
    __shared__ float Al[32 * 68];   // [p][ci]
    __shared__ float Wl[64 * 64];   // [o][ci], o >= 54 zero
    __shared__ float Ob[54 * 32];   // [o][p]
    int og = tid & 15, pg = tid >> 4;   // 4 o x 2 p per thread
    float acc[2][4];
#pragma unroll
    for (int pp = 0; pp < 2; pp++)
#pragma unroll
        for (int j = 0; j < 4; j++) acc[pp][j] = 0.0f;

    for (int cib = 0; cib < 512; cib += 64) {
        for (int s = tid; s < 2048; s += 256) {
            int kk = s & 63, pp = s >> 6;
            float v = nhwc[((size_t)(b * 64 + y) * 64 + p0 + pp) * 512 + cib + kk]
                      + share_b[cib + kk];
            Al[pp * 68 + kk] = fmaxf(v, 0.0f);
        }
        for (int s = tid; s < 64 * 64; s += 256) {
            int o = s >> 6, kk = s & 63;
            float wv = 0.0f;
            if (o < 18) wv = cls_w[o * 512 + cib + kk];
            else if (o < 54) wv = reg_w[(o - 18) * 512 + cib + kk];
            Wl[s] = wv;
        }
        __syncthreads();
        for (int kq = 0; kq < 16; kq++) {
            float4 a0 = *(const float4*)&Al[(pg * 2) * 68 + kq * 4];
            float4 a1 = *(const float4*)&Al[(pg * 2 + 1) * 68 + kq * 4];
#pragma unroll
            for (int j = 0; j < 4; j++) {
                float4 w4 = *(const float4*)&Wl[(og * 4 + j) * 64 + kq * 4];
                acc[0][j] += a0.x * w4.x + a0.y * w4.y + a0.z * w4.z + a0.w * w4.w;
                acc[1][j] += a1.x * w4.x + a1.y * w4.y + a1.z * w4.z + a1.w * w4.w;
            }
        }
        __syncthreads();
    }
#pragma unroll
    for (int pp = 0; pp < 2; pp++)
#pragma unroll
        for (int j = 0; j < 4; j++) {
            int o = og * 4 + j;
            if (o < 54) {
                float bvv = (o < 18) ? cls_b[o] : reg_b[o - 18];
                Ob[o * 32 + pg * 2 + pp] = acc[pp][j] + bvv;
            }
        }
    __syncthreads();
    float imgh = (float)d_imgh[0], imgw = (float)d_imgw[0];
    for (int task = tid; task < 288; task += 256) {
        int ta = task >> 5, p2 = task & 31;
        int x = p0 + p2;
        int a_idx = (y * 64 + x) * 9 + ta;
        // closed-form j + validity (fused k0) + anchor write
        int j = 0;
        bool myvalid = false;
#pragma unroll
        for (int tt = 0; tt < 9; tt++) {
            float c0, c1, c2, c3;
            anchor_base(tt, c0, c1, c2, c3);
            int ylo = (int)((-c0) / 16.0f) + 1;
            int yhi = (int)((imgh - c2) / 16.0f);
            int xlo = (int)((-c1) / 16.0f) + 1;
            int xhi = (int)((imgw - c3) / 16.0f);
            ylo = max(ylo, 0); yhi = min(yhi, 63);
            xlo = max(xlo, 0); xhi = min(xhi, 63);
            int Wt  = max(xhi - xlo + 1, 0);
            int nry = max(yhi - ylo + 1, 0);
            int rb  = min(max(y - ylo, 0), nry);
            bool vy = (y >= ylo) && (y <= yhi);
            int cb  = vy ? min(max(x - xlo, 0), Wt) : 0;
            bool val = vy && (x >= xlo) && (x <= xhi);
            j += rb * Wt + cb + ((tt < ta && val) ? 1 : 0);
            if (tt == ta) {
                myvalid = val;
                float4 o4;
                o4.x = c0 + 16.0f * y;
                o4.y = c1 + 16.0f * x;
                o4.z = c2 + 16.0f * y;
                o4.w = c3 + 16.0f * x;
                *(float4*)&out[OUT_ANC + a_idx * 4] = o4;
            }
        }
        if (!myvalid) continue;
        float c0 = Ob[(2 * ta) * 32 + p2], c1 = Ob[(2 * ta + 1) * 32 + p2];
        float m = fmaxf(c0, c1);
        float e0 = expf(c0 - m), e1 = expf(c1 - m);
        float sden = e0 + e1;
        float p0v = e0 / sden, p1v = e1 / sden;
        out[OUT_CLS + (size_t)(b * KANC + j) * 2 + 0] = p0v;
        out[OUT_CLS + (size_t)(b * KANC + j) * 2 + 1] = p1v;
        float l0 = Ob[(18 + 4 * ta + 0) * 32 + p2];
        float l1 = Ob[(18 + 4 * ta + 1) * 32 + p2];
        float l2 = Ob[(18 + 4 * ta + 2) * 32 + p2];
        float l3 = Ob[(18 + 4 * ta + 3) * 32 + p2];
        out[OUT_REG + (size_t)(b * KANC + j) * 4 + 0] = l0;
        out[OUT_REG + (size_t)(b * KANC + j) * 4 + 1] = l1;
        out[OUT_REG + (size_t)(b * KANC + j) * 4 + 2] = l2;
        out[OUT_REG + (size_t)(b * KANC + j) * 4 + 3] = l3;
        float b0, b1, b2, b3; anchor_base(ta, b0, b1, b2, b3);
        float ay1 = b0 + 16.0f * y, ax1 = b1 + 16.0f * x;
        float ay2 = b2 + 16.0f * y, ax2 = b3 + 16.0f * x;
        float hh = ay2 - ay1, wdt = ax2 - ax1;
        float cy = ay1 + 0.5f * hh, cx = ax1 + 0.5f * wdt;
        float ncy = l0 * hh + cy, ncx = l1 * wdt + cx;
        float nh = hh * expf(l2), nw = wdt * expf(l3);
        float by1 = fminf(fmaxf(ncy - 0.5f * nh, 0.0f), imgh);
        float bx1 = fminf(fmaxf(ncx - 0.5f * nw, 0.0f), imgw);
        float by2 = fminf(fmaxf(ncy + 0.5f * nh, 0.0f), imgh);
        float bx2 = fminf(fmaxf(ncx + 0.5f * nw, 0.0f), imgw);
        boxes_ws[(size_t)(b * KANC + j) * 4 + 0] = by1;
        boxes_ws[(size_t)(b * KANC + j) * 4 + 1] = bx1;
        boxes_ws[(size_t)(b * KANC + j) * 4 + 2] = by2;
        boxes_ws[(size_t)(b * KANC + j) * 4 + 3] = bx2;
        float hs = by2 - by1, wsz = bx2 - bx1;
        u32 key = 0;
        if (hs >= 16.0f && wsz >= 16.0f) key = __float_as_uint(p1v) + 1u;
        keys_ws[b * KANC + j] = key;
    }
}

// ---------------- K3: exact top-2000 (3-level radix) + bitonic sort ----------------
__device__ __forceinline__ void suffix_scan(u32* suf, const u32* hist, int N, int tid) {
    for (int i = tid; i < N; i += 1024) suf[i] = hist[i];
    if (tid == 0) suf[N] = 0;
    __syncthreads();
    for (int off = 1; off < N; off <<= 1) {
        u32 add0 = 0, add1 = 0;
        int i0 = tid, i1 = tid + 1024;
        if (i0 < N) add0 = (i0 + off < N) ? suf[i0 + off] : 0;
        if (i1 < N) add1 = (i1 + off < N) ? suf[i1 + off] : 0;
        __syncthreads();
        if (i0 < N) suf[i0] += add0;
        if (i1 < N) suf[i1] += add1;
        __syncthreads();
    }
}

__global__ __launch_bounds__(1024) void k3_select(const u32* __restrict__ keys_ws,
                                                  const float* __restrict__ boxes_ws,
                                                  u32* __restrict__ topkey,
                                                  float* __restrict__ topbox) {
    int b = blockIdx.x, tid = threadIdx.x;
    const u32* keys = keys_ws + (size_t)b * KANC;
    __shared__ u32 hist[2048];
    __shared__ u32 suf[2049];
    __shared__ int Ps;
    __shared__ int cnt;
    __shared__ u64 sbuf[4096];

    for (int i = tid; i < 2048; i += 1024) hist[i] = 0;
    __syncthreads();
    for (int i = tid; i < KANC; i += 1024) atomicAdd(&hist[keys[i] >> 20], 1u);
    __syncthreads();
    suffix_scan(suf, hist, 2048, tid);
    if (tid == 0) Ps = 0;
    __syncthreads();
    for (int i = tid; i < 2048; i += 1024)
        if (suf[i] >= (u32)PRE && suf[i + 1] < (u32)PRE) Ps = i;
    __syncthreads();
    u32 P1 = (u32)Ps;
    u32 quota2 = (u32)PRE - suf[P1 + 1];
    __syncthreads();

    for (int i = tid; i < 1024; i += 1024) hist[i] = 0;
    __syncthreads();
    for (int i = tid; i < KANC; i += 1024) {
        u32 k = keys[i];
        if ((k >> 20) == P1) atomicAdd(&hist[(k >> 10) & 1023u], 1u);
    }
    __syncthreads();
    suffix_scan(suf, hist, 1024, tid);
    if (tid == 0) Ps = 0;
    __syncthreads();
    for (int i = tid; i < 1024; i += 1024)
        if (suf[i] >= quota2 && suf[i + 1] < quota2) Ps = i;
    __syncthreads();
    u32 P2 = (u32)Ps;
    u32 quota3 = quota2 - suf[P2 + 1];
    __syncthreads();

    u32 pref = (P1 << 10) | P2;
    for (int i = tid; i < 1024; i += 1024) hist[i] = 0;
    __syncthreads();
    for (int i = tid; i < KANC; i += 1024) {
        u32 k = keys[i];
        if ((k >> 10) == pref) atomicAdd(&hist[k & 1023u], 1u);
    }
    __syncthreads();
    suffix_scan(suf, hist, 1024, tid);
    if (tid == 0) Ps = 0;
    __syncthreads();
    for (int i = tid; i < 1024; i += 1024)
        if (suf[i] >= quota3 && suf[i + 1] < quota3) Ps = i;
    __syncthreads();
    u32 P3 = (u32)Ps;
    u32 T = (P1 << 20) | (P2 << 10) | P3;
    u32 Tm = (T < 1u) ? 1u : T;

    for (int i = tid; i < 4096; i += 1024) sbuf[i] = 0ull;
    if (tid == 0) cnt = 0;
    __syncthreads();
    for (int i = tid; i < KANC; i += 1024) {
        u32 k = keys[i];
        if (k >= Tm) {
            int pos = atomicAdd(&cnt, 1);
            if (pos < 4096)
                sbuf[pos] = ((u64)k << 32) | (u64)(0xFFFFFFFFu - (u32)i);
        }
    }
    __syncthreads();

    for (int k2 = 2; k2 <= 4096; k2 <<= 1) {
        for (int j2 = k2 >> 1; j2 > 0; j2 >>= 1) {
            for (int i = tid; i < 4096; i += 1024) {
                int ixj = i ^ j2;
                if (ixj > i) {
                    u64 va = sbuf[i], vb = sbuf[ixj];
                    bool descRegion = ((i & k2) == 0);
                    if (descRegion ? (va < vb) : (va > vb)) {
                        sbuf[i] = vb; sbuf[ixj] = va;
                    }
                }
            }
            __syncthreads();
        }
    }

    for (int i = tid; i < PREP; i += 1024) {
        u64 v = sbuf[i];
        u32 kk = (u32)(v >> 32);
        u32 j = 0xFFFFFFFFu - (u32)(v & 0xFFFFFFFFull);
        bool good = (i < PRE) && (kk != 0);
        topkey[b * PREP + i] = good ? kk : 0;
        float4 bx = make_float4(0.0f, 0.0f, 0.0f, 0.0f);
        if (good) bx = *(const float4*)&boxes_ws[(size_t)(b * KANC + j) * 4];
        *(float4*)&topbox[(size_t)(b * PREP + i) * 4] = bx;
    }
}

// ---------------- K4: NMS suppression bitmask ----------------
__global__ __launch_bounds__(64) void k4_mask(const float* __restrict__ topbox,
                                              u64* __restrict__ mask) {
    int jb = blockIdx.x, ib = blockIdx.y, b = blockIdx.z;
    int lane = threadIdx.x;
    float4 bi = *(const float4*)&topbox[(size_t)(b * PREP + ib * 64 + lane) * 4];
    float4 bj = *(const float4*)&topbox[(size_t)(b * PREP + jb * 64 + lane) * 4];
    float ai = (bi.z - bi.x) * (bi.w - bi.y);
    float aj = (bj.z - bj.x) * (bj.w - bj.y);
    u64 word = 0;
    for (int ii = 0; ii < 64; ii++) {
        float y1 = __shfl(bi.x, ii), x1 = __shfl(bi.y, ii);
        float y2 = __shfl(bi.z, ii), x2 = __shfl(bi.w, ii);
        float aii = __shfl(ai, ii);
        float yy1 = fmaxf(y1, bj.x), xx1 = fmaxf(x1, bj.y);
        float yy2 = fminf(y2, bj.z), xx2 = fminf(x2, bj.w);
        float inter = fmaxf(yy2 - yy1, 0.0f) * fmaxf(xx2 - xx1, 0.0f);
        float iou = inter / (aii + aj - inter + 1e-9f);
        u64 bal = __ballot(iou > 0.7f);
        if (lane == ii) word = bal;
    }
    mask[(size_t)(b * PREP + ib * 64 + lane) * 32 + jb] = word;
}

// ---------------- K5: greedy scan via candidate bitmask + ctz ----------------
__global__ __launch_bounds__(64) void k5_nms(const u32* __restrict__ topkey,
                                             const float* __restrict__ topbox,
                                             const u64* __restrict__ mask,
                                             float* __restrict__ out) {
    int b = blockIdx.x;
    int lane = threadIdx.x;
    __shared__ int kept[POST];

    u64 validw = 0;
    for (int it = 0; it < 32; it++) {
        u64 wv = __ballot(topkey[b * PREP + it * 64 + lane] != 0);
        if (lane == it) validw = wv;
    }

    const u64* mb = mask + (size_t)b * PREP * 32;
    u64 remv = 0;
    const int CH = 16;
    u64 bufA[CH], bufB[CH];
    auto loadRows = [&](u64* buf, int base) {
#pragma unroll
        for (int k = 0; k < CH; k++)
            buf[k] = (lane < 32) ? mb[(size_t)(base + k) * 32 + lane] : 0ull;
    };
    int nk = 0;
    auto process = [&](u64* buf, int base) {
        int wi = base >> 6, sh = base & 63;
        u64 supw = __shfl(remv, wi);
        u64 valw = __shfl(validw, wi);
        u32 cand = (u32)(((~supw & valw) >> sh) & 0xFFFFull);
        while (cand) {
            int k = __builtin_ctz(cand);
            cand &= cand - 1;
            int i = base + k;
            remv |= buf[k];
            u64 rw = __shfl(buf[k], wi);
            cand &= ~((u32)((rw >> sh) & 0xFFFFull));
            if (lane == 0) kept[nk] = i;
            nk++;
            if (nk == POST) break;
        }
    };

    loadRows(bufA, 0);
    for (int base = 0; base < PRE && nk < POST; base += 2 * CH) {
        loadRows(bufB, base + CH);
        process(bufA, base);
        if (nk < POST && base + CH < PRE) {
            if (base + 2 * CH < PRE) loadRows(bufA, base + 2 * CH);
            process(bufB, base + CH);
        }
    }
    __syncthreads();
    for (int s = lane; s < POST; s += 64) {
        float4 bx = make_float4(0.0f, 0.0f, 0.0f, 0.0f);
        if (s < nk) bx = *(const float4*)&topbox[(size_t)(b * PREP + kept[s]) * 4];
        *(float4*)&out[OUT_ROI + (size_t)(b * POST + s) * 4] = bx;
        out[OUT_RID + b * POST + s] = (float)b;
    }
}

extern "C" void kernel_launch(void* const* d_in, const int* in_sizes, int n_in,
                              void* d_out, int out_size, void* d_ws, size_t ws_size,
                              hipStream_t stream) {
    (void)in_sizes; (void)n_in; (void)out_size; (void)ws_size;
    const float* feat    = (const float*)d_in[0];
    const float* share_w = (const float*)d_in[1];
    const float* share_b = (const float*)d_in[2];
    const float* cls_w   = (const float*)d_in[3];
    const float* cls_b   = (const float*)d_in[4];
    const float* reg_w   = (const float*)d_in[5];
    const float* reg_b   = (const float*)d_in[6];
    const int*   imgh    = (const int*)d_in[7];
    const int*   imgw    = (const int*)d_in[8];
    float* out = (float*)d_out;
    char* ws = (char*)d_ws;
    float*     nhwc   = (float*)(ws + WS_NHWC);
    ushort_t*  ft     = (ushort_t*)(ws + WS_FT);
    ushort_t*  w3     = (ushort_t*)(ws + WS_W3);
    float*     boxes  = (float*)(ws + WS_BOXES);
    u32*       keys   = (u32*)(ws + WS_KEYS);
    float*     topbox = (float*)(ws + WS_TOPBOX);
    u32*       topkey = (u32*)(ws + WS_TOPKEY);
    u64*       maskp  = (u64*)(ws + WS_MASK);

    hipMemsetAsync(nhwc, 0, (size_t)2 * 64 * 64 * 512 * 4, stream);
    t12_pre<<<1536, 256, 0, stream>>>(feat, share_w, ft, w3);
    k1_conv<<<512, 256, 0, stream>>>(ft, w3, nhwc);
    k2_heads<<<256, 256, 0, stream>>>(nhwc, share_b, cls_w, cls_b, reg_w, reg_b,
                                      out, boxes, keys, imgh, imgw);
    k3_select<<<2, 1024, 0, stream>>>(keys, boxes, topkey, topbox);
    k4_mask<<<dim3(32, 32, 2), 64, 0, stream>>>(topbox, maskp);
    k5_nms<<<2, 64, 0, stream>>>(topkey, topbox, maskp, out);
}